// Round 1
// baseline (511.974 us; speedup 1.0000x reference)
//
#include <hip/hip_runtime.h>
#include <hip/hip_bf16.h>

typedef __attribute__((ext_vector_type(8))) short short8;   // 8 x bf16 (MFMA A/B frag)
typedef __attribute__((ext_vector_type(4))) float f32x4;    // MFMA C/D frag

using bf16 = __hip_bfloat16;

static constexpr int B_ = 2, S_ = 2048, HID_ = 2048, NH_ = 16;
static constexpr int ROPE_ = 64, VDIM_ = 128, QHEAD_ = 128;
static constexpr int QLORA_ = 682, KVLORA_ = 256;
static constexpr int QLORA_P = 704;   // K padded to mult of 64
static constexpr int NQA_P = 768;     // N padded to mult of 128
static constexpr int NKVA_P = 384;
static constexpr float THETA_ = 128000.0f;
static constexpr float SCALE_ = 0.08838834764831845f;  // 1/sqrt(128)
static constexpr float EPS_ = 1e-6f;
static constexpr int BS_ = B_ * S_;   // 4096

// ---------------- elementwise f32 -> bf16 convert (vectorized) ----------------
struct bf16x4_s { bf16 x, y, z, w; };

__global__ void k_convert_bf16(const float* __restrict__ in, bf16* __restrict__ out, int n4) {
    int i = blockIdx.x * blockDim.x + threadIdx.x;
    if (i >= n4) return;
    float4 v = reinterpret_cast<const float4*>(in)[i];
    bf16x4_s o;
    o.x = __float2bfloat16(v.x); o.y = __float2bfloat16(v.y);
    o.z = __float2bfloat16(v.z); o.w = __float2bfloat16(v.w);
    reinterpret_cast<bf16x4_s*>(out)[i] = o;
}

// ---------------- W[K][N] f32  ->  Wt[Npad][Kpad] bf16 (zero-padded) ----------
__global__ void k_transpose_cvt(const float* __restrict__ W, bf16* __restrict__ Wt,
                                int Ksrc, int Nsrc, int Kpad) {
    __shared__ float tile[32][33];
    int kb = blockIdx.x * 32, nb = blockIdx.y * 32;
    int tx = threadIdx.x, ty = threadIdx.y;          // 32 x 8
    #pragma unroll
    for (int i = 0; i < 32; i += 8) {
        int k = kb + ty + i, n = nb + tx;
        tile[ty + i][tx] = (k < Ksrc && n < Nsrc) ? W[(size_t)k * Nsrc + n] : 0.0f;
    }
    __syncthreads();
    #pragma unroll
    for (int i = 0; i < 32; i += 8) {
        int n = nb + ty + i, k = kb + tx;
        Wt[(size_t)n * Kpad + k] = __float2bfloat16(tile[tx][ty + i]);
    }
}

// ---------------- RoPE cos/sin table [S][32] ----------------------------------
__global__ void k_rope_table(float* __restrict__ ct, float* __restrict__ st) {
    int idx = blockIdx.x * 256 + threadIdx.x;        // S*32 total
    int tpos = idx >> 5, j = idx & 31;
    float inv = expf(-(float)j * (logf(THETA_) / 32.0f));
    float f = (float)tpos * inv;
    ct[idx] = cosf(f);
    st[idx] = sinf(f);
}

// ---------------- GEMM: C[M][N] = A[M][K] * Bt[N][K]^T  (bf16, f32 acc) -------
// 128x128 tile, BK=64, 4 waves (2x2), 4x4 16x16x32 frags/wave.
// LDS tiles [128 rows][8 chunks of 16B], phys chunk = ch ^ (row&7) (bank-conflict-free b128).
template <typename OutT>
__launch_bounds__(256)
__global__ void gemm_bt(const bf16* __restrict__ A, const bf16* __restrict__ Bt,
                        OutT* __restrict__ C, int K, int lda, int ldb, int ldc)
{
    __shared__ bf16 As[128 * 64];
    __shared__ bf16 Bs[128 * 64];
    const int t = threadIdx.x;
    const int lane = t & 63, w = t >> 6;
    const int l15 = lane & 15, l4 = lane >> 4;
    const int wr = (w >> 1) * 64, wc = (w & 1) * 64;
    const int m0 = blockIdx.y * 128, n0 = blockIdx.x * 128;

    f32x4 acc[4][4] = {};

    for (int k0 = 0; k0 < K; k0 += 64) {
        #pragma unroll
        for (int i = 0; i < 4; ++i) {
            int cid = t + i * 256;                 // 0..1023
            int row = cid >> 3, chp = cid & 7;
            int ch = chp ^ (row & 7);              // pre-swizzled source, linear dest
            *reinterpret_cast<int4*>(reinterpret_cast<char*>(As) + cid * 16) =
                *reinterpret_cast<const int4*>(A + (size_t)(m0 + row) * lda + k0 + ch * 8);
            *reinterpret_cast<int4*>(reinterpret_cast<char*>(Bs) + cid * 16) =
                *reinterpret_cast<const int4*>(Bt + (size_t)(n0 + row) * ldb + k0 + ch * 8);
        }
        __syncthreads();
        #pragma unroll
        for (int kk = 0; kk < 2; ++kk) {
            short8 a[4], b[4];
            #pragma unroll
            for (int m = 0; m < 4; ++m) {
                int row = wr + m * 16 + l15;
                int ch = (kk * 4 + l4) ^ (row & 7);
                a[m] = *reinterpret_cast<const short8*>(
                    reinterpret_cast<const char*>(As) + row * 128 + ch * 16);
            }
            #pragma unroll
            for (int n = 0; n < 4; ++n) {
                int row = wc + n * 16 + l15;
                int ch = (kk * 4 + l4) ^ (row & 7);
                b[n] = *reinterpret_cast<const short8*>(
                    reinterpret_cast<const char*>(Bs) + row * 128 + ch * 16);
            }
            #pragma unroll
            for (int m = 0; m < 4; ++m)
                #pragma unroll
                for (int n = 0; n < 4; ++n)
                    acc[m][n] = __builtin_amdgcn_mfma_f32_16x16x32_bf16(a[m], b[n], acc[m][n], 0, 0, 0);
        }
        __syncthreads();
    }
    // C/D layout: col = lane&15, row = (lane>>4)*4 + reg  [verified m89/m91]
    #pragma unroll
    for (int m = 0; m < 4; ++m)
        #pragma unroll
        for (int n = 0; n < 4; ++n)
            #pragma unroll
            for (int j = 0; j < 4; ++j) {
                int r = m0 + wr + m * 16 + l4 * 4 + j;
                int c = n0 + wc + n * 16 + l15;
                float v = acc[m][n][j];
                if constexpr (sizeof(OutT) == 2) C[(size_t)r * ldc + c] = __float2bfloat16(v);
                else                             C[(size_t)r * ldc + c] = v;
            }
}

// ---------------- fused rmsnorm(q_a), rmsnorm(ckv), rope(k_pe) ----------------
__launch_bounds__(256)
__global__ void k_rms_rope(const bf16* __restrict__ qa, const bf16* __restrict__ ckvkpe,
                           const float* __restrict__ qln, const float* __restrict__ kvln,
                           const float* __restrict__ ct, const float* __restrict__ st,
                           bf16* __restrict__ qan, bf16* __restrict__ ckvn, bf16* __restrict__ kr)
{
    __shared__ float red[8];
    int bs = blockIdx.x;
    int t = threadIdx.x, lane = t & 63, w = t >> 6;
    int s = bs & (S_ - 1);
    const bf16* qrow = qa + (size_t)bs * NQA_P;
    const bf16* crow = ckvkpe + (size_t)bs * NKVA_P;
    float sq = 0.f, sk;
    for (int c = t; c < QLORA_; c += 256) { float v = __bfloat162float(qrow[c]); sq += v * v; }
    { float v = __bfloat162float(crow[t]); sk = v * v; }          // t in [0,256) covers all
    #pragma unroll
    for (int m = 1; m < 64; m <<= 1) { sq += __shfl_xor(sq, m); sk += __shfl_xor(sk, m); }
    if (lane == 0) { red[w] = sq; red[4 + w] = sk; }
    __syncthreads();
    sq = red[0] + red[1] + red[2] + red[3];
    sk = red[4] + red[5] + red[6] + red[7];
    float qs = rsqrtf(sq / (float)QLORA_ + EPS_);
    float ks = rsqrtf(sk / (float)KVLORA_ + EPS_);
    for (int c = t; c < QLORA_P; c += 256)
        qan[(size_t)bs * QLORA_P + c] =
            (c < QLORA_) ? __float2bfloat16(__bfloat162float(qrow[c]) * qs * qln[c])
                         : __float2bfloat16(0.0f);
    ckvn[(size_t)bs * KVLORA_ + t] = __float2bfloat16(__bfloat162float(crow[t]) * ks * kvln[t]);
    if (t < 64) {
        int j = t & 31;
        float c_ = ct[s * 32 + j], s_ = st[s * 32 + j];
        float e0 = __bfloat162float(crow[KVLORA_ + 2 * j]);      // de-interleaved RoPE
        float e1 = __bfloat162float(crow[KVLORA_ + 2 * j + 1]);
        float v = (t < 32) ? (e0 * c_ - e1 * s_) : (e1 * c_ + e0 * s_);
        kr[(size_t)bs * 64 + t] = __float2bfloat16(v);
    }
}

// ---------------- build Q (b,h,s,128): nope copy + rope(q_pe) -----------------
__global__ void k_build_q(const bf16* __restrict__ qfull, const float* __restrict__ ct,
                          const float* __restrict__ st, bf16* __restrict__ Qf)
{
    int bs = blockIdx.x, h = blockIdx.y, t = threadIdx.x;       // 128 threads
    int s = bs & (S_ - 1), b = bs >> 11;
    const bf16* src = qfull + (size_t)bs * (NH_ * QHEAD_) + h * QHEAD_;
    bf16* dst = Qf + ((size_t)(b * NH_ + h) * S_ + s) * 128;
    if (t < 64) dst[t] = src[t];
    else {
        int j = t - 64, jj = j & 31;
        float c_ = ct[s * 32 + jj], s_ = st[s * 32 + jj];
        float e0 = __bfloat162float(src[64 + 2 * jj]);
        float e1 = __bfloat162float(src[64 + 2 * jj + 1]);
        float v = (j < 32) ? (e0 * c_ - e1 * s_) : (e1 * c_ + e0 * s_);
        dst[t] = __float2bfloat16(v);
    }
}

// ---------------- build K (b,h,s,128): k_nope + broadcast roped k_pe ----------
__global__ void k_build_k(const bf16* __restrict__ kvfull, const bf16* __restrict__ kr,
                          bf16* __restrict__ Kf)
{
    int bs = blockIdx.x, h = blockIdx.y, t = threadIdx.x;       // 128 threads
    int s = bs & (S_ - 1), b = bs >> 11;
    bf16* dst = Kf + ((size_t)(b * NH_ + h) * S_ + s) * 128;
    dst[t] = (t < 64) ? kvfull[(size_t)bs * 3072 + h * 192 + t]
                      : kr[(size_t)bs * 64 + (t - 64)];
}

// ---------------- build V^T (b,h,128,S) ---------------------------------------
__global__ void k_build_vt(const bf16* __restrict__ kvfull, bf16* __restrict__ Vt)
{
    int bh = blockIdx.x;                  // 0..31
    int s0 = blockIdx.y * 64;
    int b = bh >> 4, h = bh & 15;
    __shared__ bf16 tile[64][129];
    int t = threadIdx.x;
    for (int idx = t; idx < 64 * 128; idx += 256) {
        int sl = idx >> 7, d = idx & 127;
        tile[sl][d] = kvfull[((size_t)(b * S_) + s0 + sl) * 3072 + h * 192 + 64 + d];
    }
    __syncthreads();
    for (int idx = t; idx < 64 * 128; idx += 256) {
        int d = idx >> 6, sl = idx & 63;
        Vt[((size_t)bh * 128 + d) * S_ + s0 + sl] = tile[sl][d];
    }
}

// ---------------- causal flash attention --------------------------------------
// block = (q-block of 64 rows) x (b,h). 4 waves, each owns 16 q-rows.
__launch_bounds__(256)
__global__ void k_flash(const bf16* __restrict__ Qf, const bf16* __restrict__ Kf,
                        const bf16* __restrict__ Vt, bf16* __restrict__ attn_out)
{
    __shared__ bf16 Qs[64 * 128];         // [64 rows][16 chunks], swz ch^(row&7)
    __shared__ bf16 Ks[64 * 128];
    __shared__ bf16 Vs[128 * 64];         // [128 d-rows][8 chunks]
    __shared__ bf16 Ps[4][16 * 64];       // per-wave P strip [16 rows][8 chunks]

    const int t = threadIdx.x, lane = t & 63, w = t >> 6;
    const int l15 = lane & 15, l4 = lane >> 4;
    const int qb = blockIdx.x, bh = blockIdx.y;
    const int q0 = qb * 64;
    const int b = bh >> 4, h = bh & 15;
    const bf16* Qg = Qf + ((size_t)bh * S_ + q0) * 128;
    const bf16* Kg = Kf + (size_t)bh * S_ * 128;
    const bf16* Vg = Vt + (size_t)bh * 128 * S_;

    #pragma unroll
    for (int i = 0; i < 4; ++i) {
        int cid = t + i * 256;
        int row = cid >> 4, chp = cid & 15;
        int ch = chp ^ (row & 7);
        *reinterpret_cast<int4*>(reinterpret_cast<char*>(Qs) + cid * 16) =
            *reinterpret_cast<const int4*>(Qg + (size_t)row * 128 + ch * 8);
    }
    __syncthreads();
    short8 qa_[4];                         // hoisted Q A-frags for this wave's 16 rows
    {
        int row = w * 16 + l15;
        #pragma unroll
        for (int kk = 0; kk < 4; ++kk) {
            int ch = (kk * 4 + l4) ^ (row & 7);
            qa_[kk] = *reinterpret_cast<const short8*>(
                reinterpret_cast<const char*>(Qs) + row * 256 + ch * 16);
        }
    }
    f32x4 o[8] = {};
    float m_r[4], l_r[4];
    #pragma unroll
    for (int j = 0; j < 4; ++j) { m_r[j] = -1e30f; l_r[j] = 0.f; }

    for (int kb = 0; kb <= qb; ++kb) {
        int k0 = kb * 64;
        #pragma unroll
        for (int i = 0; i < 4; ++i) {
            int cid = t + i * 256;
            int row = cid >> 4, chp = cid & 15;
            int ch = chp ^ (row & 7);
            *reinterpret_cast<int4*>(reinterpret_cast<char*>(Ks) + cid * 16) =
                *reinterpret_cast<const int4*>(Kg + (size_t)(k0 + row) * 128 + ch * 8);
        }
        #pragma unroll
        for (int i = 0; i < 4; ++i) {
            int cid = t + i * 256;
            int row = cid >> 3, chp = cid & 7;
            int ch = chp ^ (row & 7);
            *reinterpret_cast<int4*>(reinterpret_cast<char*>(Vs) + cid * 16) =
                *reinterpret_cast<const int4*>(Vg + (size_t)row * S_ + k0 + ch * 8);
        }
        __syncthreads();

        // S strip = Q(16x128) @ K^T(128x64)
        f32x4 sfr[4] = {};
        #pragma unroll
        for (int kk = 0; kk < 4; ++kk) {
            short8 bfr[4];
            #pragma unroll
            for (int n = 0; n < 4; ++n) {
                int row = n * 16 + l15;
                int ch = (kk * 4 + l4) ^ (row & 7);
                bfr[n] = *reinterpret_cast<const short8*>(
                    reinterpret_cast<const char*>(Ks) + row * 256 + ch * 16);
            }
            #pragma unroll
            for (int n = 0; n < 4; ++n)
                sfr[n] = __builtin_amdgcn_mfma_f32_16x16x32_bf16(qa_[kk], bfr[n], sfr[n], 0, 0, 0);
        }
        const bool diag = (kb == qb);
        #pragma unroll
        for (int n = 0; n < 4; ++n)
            #pragma unroll
            for (int j = 0; j < 4; ++j) {
                float v = sfr[n][j] * SCALE_;
                if (diag) {
                    int col = n * 16 + l15;
                    int row = w * 16 + l4 * 4 + j;
                    if (col > row) v = -1e30f;
                }
                sfr[n][j] = v;
            }
        float alpha[4];
        #pragma unroll
        for (int j = 0; j < 4; ++j) {
            float rm = fmaxf(fmaxf(sfr[0][j], sfr[1][j]), fmaxf(sfr[2][j], sfr[3][j]));
            rm = fmaxf(rm, __shfl_xor(rm, 1));
            rm = fmaxf(rm, __shfl_xor(rm, 2));
            rm = fmaxf(rm, __shfl_xor(rm, 4));
            rm = fmaxf(rm, __shfl_xor(rm, 8));
            float mn = fmaxf(m_r[j], rm);
            alpha[j] = __expf(m_r[j] - mn);
            m_r[j] = mn;
        }
        char* pb = reinterpret_cast<char*>(Ps[w]);
        #pragma unroll
        for (int j = 0; j < 4; ++j) {
            float rs = 0.f;
            #pragma unroll
            for (int n = 0; n < 4; ++n) {
                float p = __expf(sfr[n][j] - m_r[j]);
                sfr[n][j] = p;
                rs += p;
            }
            rs += __shfl_xor(rs, 1); rs += __shfl_xor(rs, 2);
            rs += __shfl_xor(rs, 4); rs += __shfl_xor(rs, 8);
            l_r[j] = l_r[j] * alpha[j] + rs;
            int row = l4 * 4 + j;
            #pragma unroll
            for (int n = 0; n < 4; ++n) {
                int col = n * 16 + l15;
                int ch = (col >> 3) ^ (row & 7);
                *reinterpret_cast<bf16*>(pb + row * 128 + ch * 16 + (col & 7) * 2) =
                    __float2bfloat16(sfr[n][j]);
            }
        }
        #pragma unroll
        for (int n = 0; n < 8; ++n)
            #pragma unroll
            for (int j = 0; j < 4; ++j) o[n][j] *= alpha[j];
        // O += P(16x64) @ V(64x128)
        #pragma unroll
        for (int kk = 0; kk < 2; ++kk) {
            int prow = l15;
            int pch = (kk * 4 + l4) ^ (prow & 7);
            short8 pa = *reinterpret_cast<const short8*>(pb + prow * 128 + pch * 16);
            #pragma unroll
            for (int n = 0; n < 8; ++n) {
                int row = n * 16 + l15;
                int ch = (kk * 4 + l4) ^ (row & 7);
                short8 vb = *reinterpret_cast<const short8*>(
                    reinterpret_cast<const char*>(Vs) + row * 128 + ch * 16);
                o[n] = __builtin_amdgcn_mfma_f32_16x16x32_bf16(pa, vb, o[n], 0, 0, 0);
            }
        }
        __syncthreads();
    }
    size_t obase = ((size_t)(b * S_) + q0 + w * 16) * (size_t)(NH_ * VDIM_) + h * VDIM_;
    #pragma unroll
    for (int n = 0; n < 8; ++n)
        #pragma unroll
        for (int j = 0; j < 4; ++j) {
            int r = l4 * 4 + j;
            int c = n * 16 + l15;
            attn_out[obase + (size_t)r * (NH_ * VDIM_) + c] = __float2bfloat16(o[n][j] / l_r[j]);
        }
}

// ==============================================================================
extern "C" void kernel_launch(void* const* d_in, const int* in_sizes, int n_in,
                              void* d_out, int out_size, void* d_ws, size_t ws_size,
                              hipStream_t stream)
{
    (void)in_sizes; (void)n_in; (void)out_size;
    const float* x       = (const float*)d_in[0];
    const float* q_a_w   = (const float*)d_in[1];
    const float* q_a_ln  = (const float*)d_in[2];
    const float* q_b_w   = (const float*)d_in[3];
    const float* kv_a_w  = (const float*)d_in[4];
    const float* kv_a_ln = (const float*)d_in[5];
    const float* kv_b_w  = (const float*)d_in[6];
    const float* o_w     = (const float*)d_in[7];
    float* out = (float*)d_out;

    char* ws = (char*)d_ws;
    size_t off = 0;
    auto alloc = [&](size_t bytes) -> char* {
        char* p = ws + off;
        off += (bytes + 255) & ~(size_t)255;
        return p;
    };

    bf16* xb      = (bf16*)alloc((size_t)BS_ * HID_ * 2);       // later reused as Qf (same size)
    bf16* qa_wt   = (bf16*)alloc((size_t)NQA_P * HID_ * 2);
    bf16* kva_wt  = (bf16*)alloc((size_t)NKVA_P * HID_ * 2);
    bf16* qb_wt   = (bf16*)alloc((size_t)2048 * QLORA_P * 2);
    bf16* kvb_wt  = (bf16*)alloc((size_t)3072 * KVLORA_ * 2);
    bf16* ow_t    = (bf16*)alloc((size_t)2048 * 2048 * 2);
    float* ct     = (float*)alloc((size_t)S_ * 32 * 4);
    float* st     = (float*)alloc((size_t)S_ * 32 * 4);
    char* blkI    = alloc((size_t)BS_ * NQA_P * 2);             // qa      } Kf overlays
    char* blkJ    = alloc((size_t)BS_ * NKVA_P * 2);            // ckvkpe  } I..L after
    char* blkK    = alloc((size_t)BS_ * QLORA_P * 2);           // qan     } G2/G3 done
    char* blkL    = alloc((size_t)BS_ * KVLORA_ * 2);           // ckvn    }
    bf16* kr      = (bf16*)alloc((size_t)BS_ * 64 * 2);
    bf16* qfull   = (bf16*)alloc((size_t)BS_ * 2048 * 2);       // reused as Vt (same size)
    bf16* kvfull  = (bf16*)alloc((size_t)BS_ * 3072 * 2);       // reused as attn_out (larger)

    bf16* qa     = (bf16*)blkI;
    bf16* ckvkpe = (bf16*)blkJ;
    bf16* qan    = (bf16*)blkK;
    bf16* ckvn   = (bf16*)blkL;
    bf16* Qf   = xb;
    bf16* Kf   = (bf16*)blkI;   // 16.78 MB into 17.3 MB region
    bf16* Vt   = qfull;
    bf16* attn = kvfull;

    if (ws_size < off) return;  // diagnostic guard: absmax would stay exactly 3.468750

    // stage 0: converts / transposes / tables
    k_convert_bf16<<<(BS_ * HID_ / 4 + 255) / 256, 256, 0, stream>>>(x, xb, BS_ * HID_ / 4);
    dim3 tb(32, 8);
    k_transpose_cvt<<<dim3(HID_ / 32, NQA_P / 32), tb, 0, stream>>>(q_a_w, qa_wt, HID_, QLORA_, HID_);
    k_transpose_cvt<<<dim3(HID_ / 32, NKVA_P / 32), tb, 0, stream>>>(kv_a_w, kva_wt, HID_, KVLORA_ + ROPE_, HID_);
    k_transpose_cvt<<<dim3(QLORA_P / 32, 2048 / 32), tb, 0, stream>>>(q_b_w, qb_wt, QLORA_, 2048, QLORA_P);
    k_transpose_cvt<<<dim3(KVLORA_ / 32, 3072 / 32), tb, 0, stream>>>(kv_b_w, kvb_wt, KVLORA_, 3072, KVLORA_);
    k_transpose_cvt<<<dim3(2048 / 32, 2048 / 32), tb, 0, stream>>>(o_w, ow_t, 2048, 2048, 2048);
    k_rope_table<<<S_ * 32 / 256, 256, 0, stream>>>(ct, st);

    // stage 1: down-projections
    gemm_bt<bf16><<<dim3(NQA_P / 128, BS_ / 128), 256, 0, stream>>>(xb, qa_wt, qa, HID_, HID_, HID_, NQA_P);
    gemm_bt<bf16><<<dim3(NKVA_P / 128, BS_ / 128), 256, 0, stream>>>(xb, kva_wt, ckvkpe, HID_, HID_, HID_, NKVA_P);

    // stage 2: rmsnorms + k_pe rope
    k_rms_rope<<<BS_, 256, 0, stream>>>(qa, ckvkpe, q_a_ln, kv_a_ln, ct, st, qan, ckvn, kr);

    // stage 3: up-projections
    gemm_bt<bf16><<<dim3(2048 / 128, BS_ / 128), 256, 0, stream>>>(qan, qb_wt, qfull, QLORA_P, QLORA_P, QLORA_P, 2048);
    gemm_bt<bf16><<<dim3(3072 / 128, BS_ / 128), 256, 0, stream>>>(ckvn, kvb_wt, kvfull, KVLORA_, KVLORA_, KVLORA_, 3072);

    // stage 4: assemble attention operands
    k_build_q<<<dim3(BS_, NH_), 128, 0, stream>>>(qfull, ct, st, Qf);
    k_build_k<<<dim3(BS_, NH_), 128, 0, stream>>>(kvfull, kr, Kf);
    k_build_vt<<<dim3(B_ * NH_, S_ / 64), 256, 0, stream>>>(kvfull, Vt);

    // stage 5: causal flash attention
    k_flash<<<dim3(S_ / 64, B_ * NH_), 256, 0, stream>>>(Qf, Kf, Vt, attn);

    // stage 6: output projection (f32 out)
    gemm_bt<float><<<dim3(2048 / 128, BS_ / 128), 256, 0, stream>>>(attn, ow_t, out, HID_, HID_, HID_, 2048);
}

// Round 2
// 431.590 us; speedup vs baseline: 1.1863x; 1.1863x over previous
//
#include <hip/hip_runtime.h>
#include <hip/hip_bf16.h>

typedef __attribute__((ext_vector_type(8))) short short8;   // 8 x bf16 (MFMA A/B frag)
typedef __attribute__((ext_vector_type(4))) float f32x4;    // MFMA C/D frag

using bf16 = __hip_bfloat16;

static constexpr int B_ = 2, S_ = 2048, HID_ = 2048, NH_ = 16;
static constexpr int ROPE_ = 64, VDIM_ = 128, QHEAD_ = 128;
static constexpr int QLORA_ = 682, KVLORA_ = 256;
static constexpr int QLORA_P = 704;   // K padded to mult of 64
static constexpr int NQA_P = 768;     // N padded to mult of 128
static constexpr int NKVA_P = 384;
static constexpr float THETA_ = 128000.0f;
static constexpr float SCALE_ = 0.08838834764831845f;  // 1/sqrt(128)
static constexpr float EPS_ = 1e-6f;
static constexpr int BS_ = B_ * S_;   // 4096

// async global->LDS, 16B per lane. Dest must be linear in lane order
// (wave-uniform base + lane*16); source is per-lane (pre-swizzled).
__device__ __forceinline__ void gl2lds16(const void* g, void* l) {
    __builtin_amdgcn_global_load_lds(
        (const __attribute__((address_space(1))) unsigned int*)g,
        (__attribute__((address_space(3))) unsigned int*)l, 16, 0, 0);
}

// ---------------- elementwise f32 -> bf16 convert (vectorized) ----------------
struct bf16x4_s { bf16 x, y, z, w; };

__global__ void k_convert_bf16(const float* __restrict__ in, bf16* __restrict__ out, int n4) {
    int i = blockIdx.x * blockDim.x + threadIdx.x;
    if (i >= n4) return;
    float4 v = reinterpret_cast<const float4*>(in)[i];
    bf16x4_s o;
    o.x = __float2bfloat16(v.x); o.y = __float2bfloat16(v.y);
    o.z = __float2bfloat16(v.z); o.w = __float2bfloat16(v.w);
    reinterpret_cast<bf16x4_s*>(out)[i] = o;
}

// ---------------- W[K][N] f32  ->  Wt[Npad][Kpad] bf16 (zero-padded) ----------
__global__ void k_transpose_cvt(const float* __restrict__ W, bf16* __restrict__ Wt,
                                int Ksrc, int Nsrc, int Kpad) {
    __shared__ float tile[32][33];
    int kb = blockIdx.x * 32, nb = blockIdx.y * 32;
    int tx = threadIdx.x, ty = threadIdx.y;          // 32 x 8
    #pragma unroll
    for (int i = 0; i < 32; i += 8) {
        int k = kb + ty + i, n = nb + tx;
        tile[ty + i][tx] = (k < Ksrc && n < Nsrc) ? W[(size_t)k * Nsrc + n] : 0.0f;
    }
    __syncthreads();
    #pragma unroll
    for (int i = 0; i < 32; i += 8) {
        int n = nb + ty + i, k = kb + tx;
        Wt[(size_t)n * Kpad + k] = __float2bfloat16(tile[tx][ty + i]);
    }
}

// ---------------- RoPE cos/sin table [S][32] ----------------------------------
__global__ void k_rope_table(float* __restrict__ ct, float* __restrict__ st) {
    int idx = blockIdx.x * 256 + threadIdx.x;        // S*32 total
    int tpos = idx >> 5, j = idx & 31;
    float inv = expf(-(float)j * (logf(THETA_) / 32.0f));
    float f = (float)tpos * inv;
    ct[idx] = cosf(f);
    st[idx] = sinf(f);
}

// ---------------- GEMM: C[M][N] = A[M][K] * Bt[N][K]^T  (bf16, f32 acc) -------
// 128x128 tile, BK=64, 4 waves (2x2), 4x4 16x16x32 frags/wave.
// LDS tiles [128 rows][8 chunks of 16B], phys chunk = ch ^ (row&7).
// Staging via global_load_lds w=16: linear dest, pre-swizzled source (m97 pattern).
template <typename OutT>
__launch_bounds__(256)
__global__ void gemm_bt(const bf16* __restrict__ A, const bf16* __restrict__ Bt,
                        OutT* __restrict__ C, int K, int lda, int ldb, int ldc)
{
    __shared__ bf16 As[128 * 64];
    __shared__ bf16 Bs[128 * 64];
    const int t = threadIdx.x;
    const int lane = t & 63, w = t >> 6;
    const int l15 = lane & 15, l4 = lane >> 4;
    const int wr = (w >> 1) * 64, wc = (w & 1) * 64;
    const int m0 = blockIdx.y * 128, n0 = blockIdx.x * 128;

    f32x4 acc[4][4] = {};

    for (int k0 = 0; k0 < K; k0 += 64) {
        #pragma unroll
        for (int i = 0; i < 4; ++i) {
            int cid = t + i * 256;                 // 0..1023
            int row = cid >> 3;
            int ch = (cid & 7) ^ (row & 7);        // pre-swizzled source, linear dest
            gl2lds16(A + (size_t)(m0 + row) * lda + k0 + ch * 8,
                     reinterpret_cast<char*>(As) + cid * 16);
            gl2lds16(Bt + (size_t)(n0 + row) * ldb + k0 + ch * 8,
                     reinterpret_cast<char*>(Bs) + cid * 16);
        }
        __syncthreads();
        #pragma unroll
        for (int kk = 0; kk < 2; ++kk) {
            short8 a[4], b[4];
            #pragma unroll
            for (int m = 0; m < 4; ++m) {
                int row = wr + m * 16 + l15;
                int ch = (kk * 4 + l4) ^ (row & 7);
                a[m] = *reinterpret_cast<const short8*>(
                    reinterpret_cast<const char*>(As) + row * 128 + ch * 16);
            }
            #pragma unroll
            for (int n = 0; n < 4; ++n) {
                int row = wc + n * 16 + l15;
                int ch = (kk * 4 + l4) ^ (row & 7);
                b[n] = *reinterpret_cast<const short8*>(
                    reinterpret_cast<const char*>(Bs) + row * 128 + ch * 16);
            }
            #pragma unroll
            for (int m = 0; m < 4; ++m)
                #pragma unroll
                for (int n = 0; n < 4; ++n)
                    acc[m][n] = __builtin_amdgcn_mfma_f32_16x16x32_bf16(a[m], b[n], acc[m][n], 0, 0, 0);
        }
        __syncthreads();
    }
    // C/D layout: col = lane&15, row = (lane>>4)*4 + reg  [verified m89/m91]
    #pragma unroll
    for (int m = 0; m < 4; ++m)
        #pragma unroll
        for (int n = 0; n < 4; ++n)
            #pragma unroll
            for (int j = 0; j < 4; ++j) {
                int r = m0 + wr + m * 16 + l4 * 4 + j;
                int c = n0 + wc + n * 16 + l15;
                float v = acc[m][n][j];
                if constexpr (sizeof(OutT) == 2) C[(size_t)r * ldc + c] = __float2bfloat16(v);
                else                             C[(size_t)r * ldc + c] = v;
            }
}

// ---------------- fused rmsnorm(q_a), rmsnorm(ckv), rope(k_pe) ----------------
__launch_bounds__(256)
__global__ void k_rms_rope(const bf16* __restrict__ qa, const bf16* __restrict__ ckvkpe,
                           const float* __restrict__ qln, const float* __restrict__ kvln,
                           const float* __restrict__ ct, const float* __restrict__ st,
                           bf16* __restrict__ qan, bf16* __restrict__ ckvn, bf16* __restrict__ kr)
{
    __shared__ float red[8];
    int bs = blockIdx.x;
    int t = threadIdx.x, lane = t & 63, w = t >> 6;
    int s = bs & (S_ - 1);
    const bf16* qrow = qa + (size_t)bs * NQA_P;
    const bf16* crow = ckvkpe + (size_t)bs * NKVA_P;
    float sq = 0.f, sk;
    for (int c = t; c < QLORA_; c += 256) { float v = __bfloat162float(qrow[c]); sq += v * v; }
    { float v = __bfloat162float(crow[t]); sk = v * v; }          // t in [0,256) covers all
    #pragma unroll
    for (int m = 1; m < 64; m <<= 1) { sq += __shfl_xor(sq, m); sk += __shfl_xor(sk, m); }
    if (lane == 0) { red[w] = sq; red[4 + w] = sk; }
    __syncthreads();
    sq = red[0] + red[1] + red[2] + red[3];
    sk = red[4] + red[5] + red[6] + red[7];
    float qs = rsqrtf(sq / (float)QLORA_ + EPS_);
    float ks = rsqrtf(sk / (float)KVLORA_ + EPS_);
    for (int c = t; c < QLORA_P; c += 256)
        qan[(size_t)bs * QLORA_P + c] =
            (c < QLORA_) ? __float2bfloat16(__bfloat162float(qrow[c]) * qs * qln[c])
                         : __float2bfloat16(0.0f);
    ckvn[(size_t)bs * KVLORA_ + t] = __float2bfloat16(__bfloat162float(crow[t]) * ks * kvln[t]);
    if (t < 64) {
        int j = t & 31;
        float c_ = ct[s * 32 + j], s_ = st[s * 32 + j];
        float e0 = __bfloat162float(crow[KVLORA_ + 2 * j]);      // de-interleaved RoPE
        float e1 = __bfloat162float(crow[KVLORA_ + 2 * j + 1]);
        float v = (t < 32) ? (e0 * c_ - e1 * s_) : (e1 * c_ + e0 * s_);
        kr[(size_t)bs * 64 + t] = __float2bfloat16(v);
    }
}

// ---------------- build Q (b,h,s,128): nope copy + rope(q_pe) -----------------
__global__ void k_build_q(const bf16* __restrict__ qfull, const float* __restrict__ ct,
                          const float* __restrict__ st, bf16* __restrict__ Qf)
{
    int bs = blockIdx.x, h = blockIdx.y, t = threadIdx.x;       // 128 threads
    int s = bs & (S_ - 1), b = bs >> 11;
    const bf16* src = qfull + (size_t)bs * (NH_ * QHEAD_) + h * QHEAD_;
    bf16* dst = Qf + ((size_t)(b * NH_ + h) * S_ + s) * 128;
    if (t < 64) dst[t] = src[t];
    else {
        int j = t - 64, jj = j & 31;
        float c_ = ct[s * 32 + jj], s_ = st[s * 32 + jj];
        float e0 = __bfloat162float(src[64 + 2 * jj]);
        float e1 = __bfloat162float(src[64 + 2 * jj + 1]);
        float v = (j < 32) ? (e0 * c_ - e1 * s_) : (e1 * c_ + e0 * s_);
        dst[t] = __float2bfloat16(v);
    }
}

// ---------------- build K (b,h,s,128): k_nope + broadcast roped k_pe ----------
__global__ void k_build_k(const bf16* __restrict__ kvfull, const bf16* __restrict__ kr,
                          bf16* __restrict__ Kf)
{
    int bs = blockIdx.x, h = blockIdx.y, t = threadIdx.x;       // 128 threads
    int s = bs & (S_ - 1), b = bs >> 11;
    bf16* dst = Kf + ((size_t)(b * NH_ + h) * S_ + s) * 128;
    dst[t] = (t < 64) ? kvfull[(size_t)bs * 3072 + h * 192 + t]
                      : kr[(size_t)bs * 64 + (t - 64)];
}

// ---------------- build V^T (b,h,128,S) ---------------------------------------
__global__ void k_build_vt(const bf16* __restrict__ kvfull, bf16* __restrict__ Vt)
{
    int bh = blockIdx.x;                  // 0..31
    int s0 = blockIdx.y * 64;
    int b = bh >> 4, h = bh & 15;
    __shared__ bf16 tile[64][129];
    int t = threadIdx.x;
    for (int idx = t; idx < 64 * 128; idx += 256) {
        int sl = idx >> 7, d = idx & 127;
        tile[sl][d] = kvfull[((size_t)(b * S_) + s0 + sl) * 3072 + h * 192 + 64 + d];
    }
    __syncthreads();
    for (int idx = t; idx < 64 * 128; idx += 256) {
        int d = idx >> 6, sl = idx & 63;
        Vt[((size_t)bh * 128 + d) * S_ + s0 + sl] = tile[sl][d];
    }
}

// ---------------- causal flash attention --------------------------------------
// block = 64 q-rows x (b,h). 4 waves, each owns 16 q-rows. Q lives in registers;
// K/V staged by global_load_lds. LDS 40 KiB -> 4 blocks/CU.
// qb on blockIdx.y so resident blocks per CU get spread qb (work balance).
__launch_bounds__(256, 4)
__global__ void k_flash(const bf16* __restrict__ Qf, const bf16* __restrict__ Kf,
                        const bf16* __restrict__ Vt, bf16* __restrict__ attn_out)
{
    __shared__ bf16 Ks[64 * 128];         // [64 rows][16 chunks], swz ch^(row&7)
    __shared__ bf16 Vs[128 * 64];         // [128 d-rows][8 chunks]
    __shared__ bf16 Ps[4][16 * 64];       // per-wave P strip [16 rows][8 chunks]

    const int t = threadIdx.x, lane = t & 63, w = t >> 6;
    const int l15 = lane & 15, l4 = lane >> 4;
    const int qb = blockIdx.y, bh = blockIdx.x;
    const int q0 = qb * 64;
    const int b = bh >> 4, h = bh & 15;
    const bf16* Kg = Kf + (size_t)bh * S_ * 128;
    const bf16* Vg = Vt + (size_t)bh * 128 * S_;

    // Q -> registers (one-time strided read; L2 absorbs)
    short8 qa_[4];
    {
        const bf16* qrow = Qf + ((size_t)bh * S_ + q0 + w * 16 + l15) * 128;
        #pragma unroll
        for (int kk = 0; kk < 4; ++kk)
            qa_[kk] = *reinterpret_cast<const short8*>(qrow + kk * 32 + l4 * 8);
    }

    f32x4 o[8] = {};
    float m_r[4], l_r[4];
    #pragma unroll
    for (int j = 0; j < 4; ++j) { m_r[j] = -1e30f; l_r[j] = 0.f; }
    const float SCL2 = SCALE_ * 1.4426950408889634f;   // fold log2(e): exp2 softmax

    for (int kb = 0; kb <= qb; ++kb) {
        int k0 = kb * 64;
        #pragma unroll
        for (int i = 0; i < 4; ++i) {
            int cid = t + i * 256;
            { int row = cid >> 4, ch = (cid & 15) ^ (row & 7);
              gl2lds16(Kg + (size_t)(k0 + row) * 128 + ch * 8,
                       reinterpret_cast<char*>(Ks) + cid * 16); }
            { int row = cid >> 3, ch = (cid & 7) ^ (row & 7);
              gl2lds16(Vg + (size_t)row * S_ + k0 + ch * 8,
                       reinterpret_cast<char*>(Vs) + cid * 16); }
        }
        __syncthreads();

        // S strip = Q(16x128) @ K^T(128x64)
        f32x4 sfr[4] = {};
        __builtin_amdgcn_s_setprio(1);
        #pragma unroll
        for (int kk = 0; kk < 4; ++kk) {
            short8 bfr[4];
            #pragma unroll
            for (int n = 0; n < 4; ++n) {
                int row = n * 16 + l15;
                int ch = (kk * 4 + l4) ^ (row & 7);
                bfr[n] = *reinterpret_cast<const short8*>(
                    reinterpret_cast<const char*>(Ks) + row * 256 + ch * 16);
            }
            #pragma unroll
            for (int n = 0; n < 4; ++n)
                sfr[n] = __builtin_amdgcn_mfma_f32_16x16x32_bf16(qa_[kk], bfr[n], sfr[n], 0, 0, 0);
        }
        __builtin_amdgcn_s_setprio(0);

        const bool diag = (kb == qb);
        #pragma unroll
        for (int n = 0; n < 4; ++n)
            #pragma unroll
            for (int j = 0; j < 4; ++j) {
                float v = sfr[n][j] * SCL2;            // log2-domain score
                if (diag) {
                    int col = n * 16 + l15;
                    int row = w * 16 + l4 * 4 + j;
                    if (col > row) v = -1e30f;
                }
                sfr[n][j] = v;
            }
        float alpha[4];
        #pragma unroll
        for (int j = 0; j < 4; ++j) {
            float rm = fmaxf(fmaxf(sfr[0][j], sfr[1][j]), fmaxf(sfr[2][j], sfr[3][j]));
            rm = fmaxf(rm, __shfl_xor(rm, 1));
            rm = fmaxf(rm, __shfl_xor(rm, 2));
            rm = fmaxf(rm, __shfl_xor(rm, 4));
            rm = fmaxf(rm, __shfl_xor(rm, 8));
            float mn = fmaxf(m_r[j], rm);
            alpha[j] = exp2f(m_r[j] - mn);
            m_r[j] = mn;
        }
        char* pb = reinterpret_cast<char*>(Ps[w]);
        #pragma unroll
        for (int j = 0; j < 4; ++j) {
            float rs = 0.f;
            #pragma unroll
            for (int n = 0; n < 4; ++n) {
                float p = exp2f(sfr[n][j] - m_r[j]);
                sfr[n][j] = p;
                rs += p;
            }
            rs += __shfl_xor(rs, 1); rs += __shfl_xor(rs, 2);
            rs += __shfl_xor(rs, 4); rs += __shfl_xor(rs, 8);
            l_r[j] = l_r[j] * alpha[j] + rs;
            int row = l4 * 4 + j;
            #pragma unroll
            for (int n = 0; n < 4; ++n) {
                int col = n * 16 + l15;
                int ch = (col >> 3) ^ (row & 7);
                *reinterpret_cast<bf16*>(pb + row * 128 + ch * 16 + (col & 7) * 2) =
                    __float2bfloat16(sfr[n][j]);
            }
        }
        #pragma unroll
        for (int n = 0; n < 8; ++n)
            #pragma unroll
            for (int j = 0; j < 4; ++j) o[n][j] *= alpha[j];
        // O += P(16x64) @ V(64x128)
        __builtin_amdgcn_s_setprio(1);
        #pragma unroll
        for (int kk = 0; kk < 2; ++kk) {
            int pch = (kk * 4 + l4) ^ (l15 & 7);
            short8 pa = *reinterpret_cast<const short8*>(pb + l15 * 128 + pch * 16);
            #pragma unroll
            for (int n = 0; n < 8; ++n) {
                int row = n * 16 + l15;
                int ch = (kk * 4 + l4) ^ (row & 7);
                short8 vb = *reinterpret_cast<const short8*>(
                    reinterpret_cast<const char*>(Vs) + row * 128 + ch * 16);
                o[n] = __builtin_amdgcn_mfma_f32_16x16x32_bf16(pa, vb, o[n], 0, 0, 0);
            }
        }
        __builtin_amdgcn_s_setprio(0);
        __syncthreads();
    }
    size_t obase = ((size_t)(b * S_) + q0 + w * 16) * (size_t)(NH_ * VDIM_) + h * VDIM_;
    #pragma unroll
    for (int n = 0; n < 8; ++n)
        #pragma unroll
        for (int j = 0; j < 4; ++j) {
            int r = l4 * 4 + j;
            int c = n * 16 + l15;
            attn_out[obase + (size_t)r * (NH_ * VDIM_) + c] = __float2bfloat16(o[n][j] / l_r[j]);
        }
}

// ==============================================================================
extern "C" void kernel_launch(void* const* d_in, const int* in_sizes, int n_in,
                              void* d_out, int out_size, void* d_ws, size_t ws_size,
                              hipStream_t stream)
{
    (void)in_sizes; (void)n_in; (void)out_size;
    const float* x       = (const float*)d_in[0];
    const float* q_a_w   = (const float*)d_in[1];
    const float* q_a_ln  = (const float*)d_in[2];
    const float* q_b_w   = (const float*)d_in[3];
    const float* kv_a_w  = (const float*)d_in[4];
    const float* kv_a_ln = (const float*)d_in[5];
    const float* kv_b_w  = (const float*)d_in[6];
    const float* o_w     = (const float*)d_in[7];
    float* out = (float*)d_out;

    char* ws = (char*)d_ws;
    size_t off = 0;
    auto alloc = [&](size_t bytes) -> char* {
        char* p = ws + off;
        off += (bytes + 255) & ~(size_t)255;
        return p;
    };

    bf16* xb      = (bf16*)alloc((size_t)BS_ * HID_ * 2);       // later reused as Qf (same size)
    bf16* qa_wt   = (bf16*)alloc((size_t)NQA_P * HID_ * 2);
    bf16* kva_wt  = (bf16*)alloc((size_t)NKVA_P * HID_ * 2);
    bf16* qb_wt   = (bf16*)alloc((size_t)2048 * QLORA_P * 2);
    bf16* kvb_wt  = (bf16*)alloc((size_t)3072 * KVLORA_ * 2);
    bf16* ow_t    = (bf16*)alloc((size_t)2048 * 2048 * 2);
    float* ct     = (float*)alloc((size_t)S_ * 32 * 4);
    float* st     = (float*)alloc((size_t)S_ * 32 * 4);
    char* blkI    = alloc((size_t)BS_ * NQA_P * 2);             // qa      } Kf overlays
    char* blkJ    = alloc((size_t)BS_ * NKVA_P * 2);            // ckvkpe  } I..L after
    char* blkK    = alloc((size_t)BS_ * QLORA_P * 2);           // qan     } G2/G3 done
    char* blkL    = alloc((size_t)BS_ * KVLORA_ * 2);           // ckvn    }
    bf16* kr      = (bf16*)alloc((size_t)BS_ * 64 * 2);
    bf16* qfull   = (bf16*)alloc((size_t)BS_ * 2048 * 2);       // reused as Vt (same size)
    bf16* kvfull  = (bf16*)alloc((size_t)BS_ * 3072 * 2);       // reused as attn_out (larger)

    bf16* qa     = (bf16*)blkI;
    bf16* ckvkpe = (bf16*)blkJ;
    bf16* qan    = (bf16*)blkK;
    bf16* ckvn   = (bf16*)blkL;
    bf16* Qf   = xb;
    bf16* Kf   = (bf16*)blkI;   // 16.78 MB into 17.3 MB region
    bf16* Vt   = qfull;
    bf16* attn = kvfull;

    if (ws_size < off) return;  // diagnostic guard: absmax would stay exactly 3.468750

    // stage 0: converts / transposes / tables
    k_convert_bf16<<<(BS_ * HID_ / 4 + 255) / 256, 256, 0, stream>>>(x, xb, BS_ * HID_ / 4);
    dim3 tb(32, 8);
    k_transpose_cvt<<<dim3(HID_ / 32, NQA_P / 32), tb, 0, stream>>>(q_a_w, qa_wt, HID_, QLORA_, HID_);
    k_transpose_cvt<<<dim3(HID_ / 32, NKVA_P / 32), tb, 0, stream>>>(kv_a_w, kva_wt, HID_, KVLORA_ + ROPE_, HID_);
    k_transpose_cvt<<<dim3(QLORA_P / 32, 2048 / 32), tb, 0, stream>>>(q_b_w, qb_wt, QLORA_, 2048, QLORA_P);
    k_transpose_cvt<<<dim3(KVLORA_ / 32, 3072 / 32), tb, 0, stream>>>(kv_b_w, kvb_wt, KVLORA_, 3072, KVLORA_);
    k_transpose_cvt<<<dim3(2048 / 32, 2048 / 32), tb, 0, stream>>>(o_w, ow_t, 2048, 2048, 2048);
    k_rope_table<<<S_ * 32 / 256, 256, 0, stream>>>(ct, st);

    // stage 1: down-projections
    gemm_bt<bf16><<<dim3(NQA_P / 128, BS_ / 128), 256, 0, stream>>>(xb, qa_wt, qa, HID_, HID_, HID_, NQA_P);
    gemm_bt<bf16><<<dim3(NKVA_P / 128, BS_ / 128), 256, 0, stream>>>(xb, kva_wt, ckvkpe, HID_, HID_, HID_, NKVA_P);

    // stage 2: rmsnorms + k_pe rope
    k_rms_rope<<<BS_, 256, 0, stream>>>(qa, ckvkpe, q_a_ln, kv_a_ln, ct, st, qan, ckvn, kr);

    // stage 3: up-projections
    gemm_bt<bf16><<<dim3(2048 / 128, BS_ / 128), 256, 0, stream>>>(qan, qb_wt, qfull, QLORA_P, QLORA_P, QLORA_P, 2048);
    gemm_bt<bf16><<<dim3(3072 / 128, BS_ / 128), 256, 0, stream>>>(ckvn, kvb_wt, kvfull, KVLORA_, KVLORA_, KVLORA_, 3072);

    // stage 4: assemble attention operands
    k_build_q<<<dim3(BS_, NH_), 128, 0, stream>>>(qfull, ct, st, Qf);
    k_build_k<<<dim3(BS_, NH_), 128, 0, stream>>>(kvfull, kr, Kf);
    k_build_vt<<<dim3(B_ * NH_, S_ / 64), 256, 0, stream>>>(kvfull, Vt);

    // stage 5: causal flash attention (qb on y for CU work balance)
    k_flash<<<dim3(B_ * NH_, S_ / 64), 256, 0, stream>>>(Qf, Kf, Vt, attn);

    // stage 6: output projection (f32 out)
    gemm_bt<float><<<dim3(2048 / 128, BS_ / 128), 256, 0, stream>>>(attn, ow_t, out, HID_, HID_, HID_, 2048);
}

// Round 3
// 343.278 us; speedup vs baseline: 1.4914x; 1.2573x over previous
//
#include <hip/hip_runtime.h>
#include <hip/hip_bf16.h>

typedef __attribute__((ext_vector_type(8))) short short8;   // 8 x bf16 (MFMA A/B frag)
typedef __attribute__((ext_vector_type(4))) float f32x4;    // MFMA C/D frag

using bf16 = __hip_bfloat16;

static constexpr int B_ = 2, S_ = 2048, HID_ = 2048, NH_ = 16;
static constexpr int ROPE_ = 64, VDIM_ = 128, QHEAD_ = 128;
static constexpr int QLORA_ = 682, KVLORA_ = 256;
static constexpr int QLORA_P = 704;   // K padded to mult of 64
static constexpr int NQA_P = 768;     // N padded to mult of 128
static constexpr int NKVA_P = 384;
static constexpr float THETA_ = 128000.0f;
static constexpr float SCALE_ = 0.08838834764831845f;  // 1/sqrt(128)
static constexpr float EPS_ = 1e-6f;
static constexpr int BS_ = B_ * S_;   // 4096

// async global->LDS, 16B per lane. Dest must be linear in lane order
// (wave-uniform base + lane*16); source is per-lane (may be swizzled/gathered).
__device__ __forceinline__ void gl2lds16(const void* g, void* l) {
    __builtin_amdgcn_global_load_lds(
        (const __attribute__((address_space(1))) unsigned int*)g,
        (__attribute__((address_space(3))) unsigned int*)l, 16, 0, 0);
}

// ---------------- elementwise f32 -> bf16 convert (vectorized) ----------------
struct bf16x4_s { bf16 x, y, z, w; };

__global__ void k_convert_bf16(const float* __restrict__ in, bf16* __restrict__ out, int n4) {
    int i = blockIdx.x * blockDim.x + threadIdx.x;
    if (i >= n4) return;
    float4 v = reinterpret_cast<const float4*>(in)[i];
    bf16x4_s o;
    o.x = __float2bfloat16(v.x); o.y = __float2bfloat16(v.y);
    o.z = __float2bfloat16(v.z); o.w = __float2bfloat16(v.w);
    reinterpret_cast<bf16x4_s*>(out)[i] = o;
}

// ---------------- W[K][N] f32  ->  Wt[Npad][Kpad] bf16 (zero-padded) ----------
__global__ void k_transpose_cvt(const float* __restrict__ W, bf16* __restrict__ Wt,
                                int Ksrc, int Nsrc, int Kpad) {
    __shared__ float tile[32][33];
    int kb = blockIdx.x * 32, nb = blockIdx.y * 32;
    int tx = threadIdx.x, ty = threadIdx.y;          // 32 x 8
    #pragma unroll
    for (int i = 0; i < 32; i += 8) {
        int k = kb + ty + i, n = nb + tx;
        tile[ty + i][tx] = (k < Ksrc && n < Nsrc) ? W[(size_t)k * Nsrc + n] : 0.0f;
    }
    __syncthreads();
    #pragma unroll
    for (int i = 0; i < 32; i += 8) {
        int n = nb + ty + i, k = kb + tx;
        Wt[(size_t)n * Kpad + k] = __float2bfloat16(tile[tx][ty + i]);
    }
}

// ---------------- RoPE cos/sin table [S][32] ----------------------------------
__global__ void k_rope_table(float* __restrict__ ct, float* __restrict__ st) {
    int idx = blockIdx.x * 256 + threadIdx.x;        // S*32 total
    int tpos = idx >> 5, j = idx & 31;
    float inv = expf(-(float)j * (logf(THETA_) / 32.0f));
    float f = (float)tpos * inv;
    ct[idx] = cosf(f);
    st[idx] = sinf(f);
}

// ---------------- GEMM: C[M][N] = A[M][K] * Bt[N][K]^T  (bf16, f32 acc) -------
// 128x128 tile, BK=64, 4 waves (2x2), 4x4 16x16x32 frags/wave.
// LDS tiles [128 rows][8 chunks of 16B], phys chunk = ch ^ (row&7).
// Staging via global_load_lds w=16: linear dest, pre-swizzled source (m97 pattern).
template <typename OutT>
__launch_bounds__(256)
__global__ void gemm_bt(const bf16* __restrict__ A, const bf16* __restrict__ Bt,
                        OutT* __restrict__ C, int K, int lda, int ldb, int ldc)
{
    __shared__ bf16 As[128 * 64];
    __shared__ bf16 Bs[128 * 64];
    const int t = threadIdx.x;
    const int lane = t & 63, w = t >> 6;
    const int l15 = lane & 15, l4 = lane >> 4;
    const int wr = (w >> 1) * 64, wc = (w & 1) * 64;
    const int m0 = blockIdx.y * 128, n0 = blockIdx.x * 128;

    f32x4 acc[4][4] = {};

    for (int k0 = 0; k0 < K; k0 += 64) {
        #pragma unroll
        for (int i = 0; i < 4; ++i) {
            int cid = t + i * 256;                 // 0..1023
            int row = cid >> 3;
            int ch = (cid & 7) ^ (row & 7);        // pre-swizzled source, linear dest
            gl2lds16(A + (size_t)(m0 + row) * lda + k0 + ch * 8,
                     reinterpret_cast<char*>(As) + cid * 16);
            gl2lds16(Bt + (size_t)(n0 + row) * ldb + k0 + ch * 8,
                     reinterpret_cast<char*>(Bs) + cid * 16);
        }
        __syncthreads();
        #pragma unroll
        for (int kk = 0; kk < 2; ++kk) {
            short8 a[4], b[4];
            #pragma unroll
            for (int m = 0; m < 4; ++m) {
                int row = wr + m * 16 + l15;
                int ch = (kk * 4 + l4) ^ (row & 7);
                a[m] = *reinterpret_cast<const short8*>(
                    reinterpret_cast<const char*>(As) + row * 128 + ch * 16);
            }
            #pragma unroll
            for (int n = 0; n < 4; ++n) {
                int row = wc + n * 16 + l15;
                int ch = (kk * 4 + l4) ^ (row & 7);
                b[n] = *reinterpret_cast<const short8*>(
                    reinterpret_cast<const char*>(Bs) + row * 128 + ch * 16);
            }
            #pragma unroll
            for (int m = 0; m < 4; ++m)
                #pragma unroll
                for (int n = 0; n < 4; ++n)
                    acc[m][n] = __builtin_amdgcn_mfma_f32_16x16x32_bf16(a[m], b[n], acc[m][n], 0, 0, 0);
        }
        __syncthreads();
    }
    // C/D layout: col = lane&15, row = (lane>>4)*4 + reg  [verified m89/m91]
    #pragma unroll
    for (int m = 0; m < 4; ++m)
        #pragma unroll
        for (int n = 0; n < 4; ++n)
            #pragma unroll
            for (int j = 0; j < 4; ++j) {
                int r = m0 + wr + m * 16 + l4 * 4 + j;
                int c = n0 + wc + n * 16 + l15;
                float v = acc[m][n][j];
                if constexpr (sizeof(OutT) == 2) C[(size_t)r * ldc + c] = __float2bfloat16(v);
                else                             C[(size_t)r * ldc + c] = v;
            }
}

// ---------------- fused rmsnorm(q_a), rmsnorm(ckv), rope(k_pe) ----------------
__launch_bounds__(256)
__global__ void k_rms_rope(const bf16* __restrict__ qa, const bf16* __restrict__ ckvkpe,
                           const float* __restrict__ qln, const float* __restrict__ kvln,
                           const float* __restrict__ ct, const float* __restrict__ st,
                           bf16* __restrict__ qan, bf16* __restrict__ ckvn, bf16* __restrict__ kr)
{
    __shared__ float red[8];
    int bs = blockIdx.x;
    int t = threadIdx.x, lane = t & 63, w = t >> 6;
    int s = bs & (S_ - 1);
    const bf16* qrow = qa + (size_t)bs * NQA_P;
    const bf16* crow = ckvkpe + (size_t)bs * NKVA_P;
    float sq = 0.f, sk;
    for (int c = t; c < QLORA_; c += 256) { float v = __bfloat162float(qrow[c]); sq += v * v; }
    { float v = __bfloat162float(crow[t]); sk = v * v; }          // t in [0,256) covers all
    #pragma unroll
    for (int m = 1; m < 64; m <<= 1) { sq += __shfl_xor(sq, m); sk += __shfl_xor(sk, m); }
    if (lane == 0) { red[w] = sq; red[4 + w] = sk; }
    __syncthreads();
    sq = red[0] + red[1] + red[2] + red[3];
    sk = red[4] + red[5] + red[6] + red[7];
    float qs = rsqrtf(sq / (float)QLORA_ + EPS_);
    float ks = rsqrtf(sk / (float)KVLORA_ + EPS_);
    for (int c = t; c < QLORA_P; c += 256)
        qan[(size_t)bs * QLORA_P + c] =
            (c < QLORA_) ? __float2bfloat16(__bfloat162float(qrow[c]) * qs * qln[c])
                         : __float2bfloat16(0.0f);
    ckvn[(size_t)bs * KVLORA_ + t] = __float2bfloat16(__bfloat162float(crow[t]) * ks * kvln[t]);
    if (t < 64) {
        int j = t & 31;
        float c_ = ct[s * 32 + j], s_ = st[s * 32 + j];
        float e0 = __bfloat162float(crow[KVLORA_ + 2 * j]);      // de-interleaved RoPE
        float e1 = __bfloat162float(crow[KVLORA_ + 2 * j + 1]);
        float v = (t < 32) ? (e0 * c_ - e1 * s_) : (e1 * c_ + e0 * s_);
        kr[(size_t)bs * 64 + t] = __float2bfloat16(v);
    }
}

// ---------------- build Q (b,h,s,128): nope copy + rope(q_pe) -----------------
__global__ void k_build_q(const bf16* __restrict__ qfull, const float* __restrict__ ct,
                          const float* __restrict__ st, bf16* __restrict__ Qf)
{
    int bs = blockIdx.x, h = blockIdx.y, t = threadIdx.x;       // 128 threads
    int s = bs & (S_ - 1), b = bs >> 11;
    const bf16* src = qfull + (size_t)bs * (NH_ * QHEAD_) + h * QHEAD_;
    bf16* dst = Qf + ((size_t)(b * NH_ + h) * S_ + s) * 128;
    if (t < 64) dst[t] = src[t];
    else {
        int j = t - 64, jj = j & 31;
        float c_ = ct[s * 32 + jj], s_ = st[s * 32 + jj];
        float e0 = __bfloat162float(src[64 + 2 * jj]);
        float e1 = __bfloat162float(src[64 + 2 * jj + 1]);
        float v = (j < 32) ? (e0 * c_ - e1 * s_) : (e1 * c_ + e0 * s_);
        dst[t] = __float2bfloat16(v);
    }
}

// ---------------- build V^T (b,h,128,S) ---------------------------------------
__global__ void k_build_vt(const bf16* __restrict__ kvfull, bf16* __restrict__ Vt)
{
    int bh = blockIdx.x;                  // 0..31
    int s0 = blockIdx.y * 64;
    int b = bh >> 4, h = bh & 15;
    __shared__ bf16 tile[64][129];
    int t = threadIdx.x;
    for (int idx = t; idx < 64 * 128; idx += 256) {
        int sl = idx >> 7, d = idx & 127;
        tile[sl][d] = kvfull[((size_t)(b * S_) + s0 + sl) * 3072 + h * 192 + 64 + d];
    }
    __syncthreads();
    for (int idx = t; idx < 64 * 128; idx += 256) {
        int d = idx >> 6, sl = idx & 63;
        Vt[((size_t)bh * 128 + d) * S_ + s0 + sl] = tile[sl][d];
    }
}

// ---------------- causal flash attention --------------------------------------
// block = 128 q-rows x (b,h). 8 waves, each owns 16 q-rows. Q in registers.
// K staged directly from kvfull+kr (gathered per-lane source); V from Vt.
// Double-buffered K/V, one __syncthreads per tile (2-phase pipeline, T3-lite).
// LDS 80 KiB -> 2 blocks/CU.
__launch_bounds__(512, 4)
__global__ void k_flash(const bf16* __restrict__ Qf, const bf16* __restrict__ kvfull,
                        const bf16* __restrict__ kr, const bf16* __restrict__ Vt,
                        bf16* __restrict__ attn_out)
{
    __shared__ bf16 Ks[2][64 * 128];      // [64 k-rows][16 chunks], swz ch^(row&7)
    __shared__ bf16 Vs[2][128 * 64];      // [128 d-rows][8 chunks]
    __shared__ bf16 Ps[8][16 * 64];       // per-wave P strip [16 rows][8 chunks]

    const int t = threadIdx.x, lane = t & 63, w = t >> 6;
    const int l15 = lane & 15, l4 = lane >> 4;
    // pair qb's so the 2 co-resident blocks/CU sum to ~constant work
    const int qb = (blockIdx.y < 8) ? blockIdx.y : (23 - blockIdx.y);
    const int bh = blockIdx.x;
    const int q0 = qb * 128;
    const int b = bh >> 4, h = bh & 15;
    const int r0 = q0 + w * 16;           // wave's first q-row
    const bf16* Vg = Vt + (size_t)bh * 128 * S_;

    // Q -> registers (one-time strided read; L2/L3 absorbs)
    short8 qa_[4];
    {
        const bf16* qrow = Qf + ((size_t)bh * S_ + r0 + l15) * 128;
        #pragma unroll
        for (int kk = 0; kk < 4; ++kk)
            qa_[kk] = *reinterpret_cast<const short8*>(qrow + kk * 32 + l4 * 8);
    }

    // stage K tile: nope cols [0,64) from kvfull, pe cols [64,128) from kr
    auto stageK = [&](int k0, int buf) {
        #pragma unroll
        for (int i = 0; i < 2; ++i) {
            int cid = t + i * 512;                 // 0..1023
            int row = cid >> 4;
            int ch = (cid & 15) ^ (row & 7);       // pre-swizzled source, linear dest
            size_t bs = (size_t)(b * S_ + k0 + row);
            const bf16* src = (ch < 8)
                ? kvfull + bs * 3072 + h * 192 + ch * 8
                : kr + bs * 64 + (ch - 8) * 8;
            gl2lds16(src, reinterpret_cast<char*>(Ks[buf]) + cid * 16);
        }
    };
    auto stageV = [&](int k0, int buf) {
        #pragma unroll
        for (int i = 0; i < 2; ++i) {
            int cid = t + i * 512;
            int row = cid >> 3;                    // d-row 0..127
            int ch = (cid & 7) ^ (row & 7);
            gl2lds16(Vg + (size_t)row * S_ + k0 + ch * 8,
                     reinterpret_cast<char*>(Vs[buf]) + cid * 16);
        }
    };

    const int NT = qb * 2 + 2;                     // 64-wide K tiles
    stageK(0, 0); stageV(0, 0);
    __syncthreads();

    f32x4 o[8] = {};
    float m_r[4], l_r[4];
    #pragma unroll
    for (int j = 0; j < 4; ++j) { m_r[j] = -1e30f; l_r[j] = 0.f; }
    const float SCL2 = SCALE_ * 1.4426950408889634f;   // fold log2(e): exp2 softmax

    int cur = 0;
    for (int kb = 0; kb < NT; ++kb) {
        const int k0 = kb * 64;
        if (kb + 1 < NT) { stageK(k0 + 64, cur ^ 1); stageV(k0 + 64, cur ^ 1); }

        if (k0 <= r0 + 15) {                       // skip fully-masked tiles for this wave
            // S strip = Q(16x128) @ K^T(128x64)
            f32x4 sfr[4] = {};
            __builtin_amdgcn_s_setprio(1);
            #pragma unroll
            for (int kk = 0; kk < 4; ++kk) {
                short8 bfr[4];
                #pragma unroll
                for (int n = 0; n < 4; ++n) {
                    int row = n * 16 + l15;
                    int ch = (kk * 4 + l4) ^ (row & 7);
                    bfr[n] = *reinterpret_cast<const short8*>(
                        reinterpret_cast<const char*>(Ks[cur]) + row * 256 + ch * 16);
                }
                #pragma unroll
                for (int n = 0; n < 4; ++n)
                    sfr[n] = __builtin_amdgcn_mfma_f32_16x16x32_bf16(qa_[kk], bfr[n], sfr[n], 0, 0, 0);
            }
            __builtin_amdgcn_s_setprio(0);

            const bool needMask = (k0 + 63 > r0);
            #pragma unroll
            for (int n = 0; n < 4; ++n)
                #pragma unroll
                for (int j = 0; j < 4; ++j) {
                    float v = sfr[n][j] * SCL2;            // log2-domain score
                    if (needMask) {
                        int col = k0 + n * 16 + l15;
                        int row = r0 + l4 * 4 + j;
                        if (col > row) v = -1e30f;
                    }
                    sfr[n][j] = v;
                }

            // online max with defer-rescale (T13, THR=8 in log2 domain)
            float rm[4];
            bool grow = false;
            #pragma unroll
            for (int j = 0; j < 4; ++j) {
                float r = fmaxf(fmaxf(sfr[0][j], sfr[1][j]), fmaxf(sfr[2][j], sfr[3][j]));
                r = fmaxf(r, __shfl_xor(r, 1));
                r = fmaxf(r, __shfl_xor(r, 2));
                r = fmaxf(r, __shfl_xor(r, 4));
                r = fmaxf(r, __shfl_xor(r, 8));
                rm[j] = r;
                grow |= (r > m_r[j] + 8.0f);
            }
            if (__ballot(grow)) {
                #pragma unroll
                for (int j = 0; j < 4; ++j) {
                    float mn = fmaxf(m_r[j], rm[j]);
                    float alpha = exp2f(m_r[j] - mn);
                    m_r[j] = mn;
                    l_r[j] *= alpha;
                    #pragma unroll
                    for (int n = 0; n < 8; ++n) o[n][j] *= alpha;
                }
            }

            char* pb = reinterpret_cast<char*>(Ps[w]);
            #pragma unroll
            for (int j = 0; j < 4; ++j) {
                float rs = 0.f;
                #pragma unroll
                for (int n = 0; n < 4; ++n) {
                    float p = exp2f(sfr[n][j] - m_r[j]);
                    sfr[n][j] = p;
                    rs += p;
                }
                rs += __shfl_xor(rs, 1); rs += __shfl_xor(rs, 2);
                rs += __shfl_xor(rs, 4); rs += __shfl_xor(rs, 8);
                l_r[j] += rs;
                int row = l4 * 4 + j;
                #pragma unroll
                for (int n = 0; n < 4; ++n) {
                    int col = n * 16 + l15;
                    int ch = (col >> 3) ^ (row & 7);
                    *reinterpret_cast<bf16*>(pb + row * 128 + ch * 16 + (col & 7) * 2) =
                        __float2bfloat16(sfr[n][j]);
                }
            }
            // O += P(16x64) @ V(64x128)
            __builtin_amdgcn_s_setprio(1);
            #pragma unroll
            for (int kk = 0; kk < 2; ++kk) {
                int pch = (kk * 4 + l4) ^ (l15 & 7);
                short8 pa = *reinterpret_cast<const short8*>(pb + l15 * 128 + pch * 16);
                #pragma unroll
                for (int n = 0; n < 8; ++n) {
                    int row = n * 16 + l15;
                    int ch = (kk * 4 + l4) ^ (row & 7);
                    short8 vb = *reinterpret_cast<const short8*>(
                        reinterpret_cast<const char*>(Vs[cur]) + row * 128 + ch * 16);
                    o[n] = __builtin_amdgcn_mfma_f32_16x16x32_bf16(pa, vb, o[n], 0, 0, 0);
                }
            }
            __builtin_amdgcn_s_setprio(0);
        }
        __syncthreads();     // drains next-tile loads (they flew under compute) + syncs
        cur ^= 1;
    }

    size_t obase = ((size_t)(b * S_) + q0 + w * 16) * (size_t)(NH_ * VDIM_) + h * VDIM_;
    #pragma unroll
    for (int n = 0; n < 8; ++n)
        #pragma unroll
        for (int j = 0; j < 4; ++j) {
            int r = l4 * 4 + j;
            int c = n * 16 + l15;
            attn_out[obase + (size_t)r * (NH_ * VDIM_) + c] = __float2bfloat16(o[n][j] / l_r[j]);
        }
}

// ==============================================================================
extern "C" void kernel_launch(void* const* d_in, const int* in_sizes, int n_in,
                              void* d_out, int out_size, void* d_ws, size_t ws_size,
                              hipStream_t stream)
{
    (void)in_sizes; (void)n_in; (void)out_size;
    const float* x       = (const float*)d_in[0];
    const float* q_a_w   = (const float*)d_in[1];
    const float* q_a_ln  = (const float*)d_in[2];
    const float* q_b_w   = (const float*)d_in[3];
    const float* kv_a_w  = (const float*)d_in[4];
    const float* kv_a_ln = (const float*)d_in[5];
    const float* kv_b_w  = (const float*)d_in[6];
    const float* o_w     = (const float*)d_in[7];
    float* out = (float*)d_out;

    char* ws = (char*)d_ws;
    size_t off = 0;
    auto alloc = [&](size_t bytes) -> char* {
        char* p = ws + off;
        off += (bytes + 255) & ~(size_t)255;
        return p;
    };

    bf16* xb      = (bf16*)alloc((size_t)BS_ * HID_ * 2);       // later reused as Qf (same size)
    bf16* qa_wt   = (bf16*)alloc((size_t)NQA_P * HID_ * 2);
    bf16* kva_wt  = (bf16*)alloc((size_t)NKVA_P * HID_ * 2);
    bf16* qb_wt   = (bf16*)alloc((size_t)2048 * QLORA_P * 2);
    bf16* kvb_wt  = (bf16*)alloc((size_t)3072 * KVLORA_ * 2);
    bf16* ow_t    = (bf16*)alloc((size_t)2048 * 2048 * 2);
    float* ct     = (float*)alloc((size_t)S_ * 32 * 4);
    float* st     = (float*)alloc((size_t)S_ * 32 * 4);
    char* blkI    = alloc((size_t)BS_ * NQA_P * 2);             // qa      } attn out overlays
    char* blkJ    = alloc((size_t)BS_ * NKVA_P * 2);            // ckvkpe  } I..L after
    char* blkK    = alloc((size_t)BS_ * QLORA_P * 2);           // qan     } stages 2/3 done
    char* blkL    = alloc((size_t)BS_ * KVLORA_ * 2);           // ckvn    }
    bf16* kr      = (bf16*)alloc((size_t)BS_ * 64 * 2);
    bf16* qfull   = (bf16*)alloc((size_t)BS_ * 2048 * 2);       // reused as Vt (same size)
    bf16* kvfull  = (bf16*)alloc((size_t)BS_ * 3072 * 2);       // read by flash (K-nope + V src)

    bf16* qa     = (bf16*)blkI;
    bf16* ckvkpe = (bf16*)blkJ;
    bf16* qan    = (bf16*)blkK;
    bf16* ckvn   = (bf16*)blkL;
    bf16* Qf   = xb;
    bf16* Vt   = qfull;
    bf16* attn = (bf16*)blkI;   // 16.78 MB into 17.3 MB region I..L (dead after stage 3)

    if (ws_size < off) return;  // diagnostic guard: absmax would stay exactly 3.468750

    // stage 0: converts / transposes / tables
    k_convert_bf16<<<(BS_ * HID_ / 4 + 255) / 256, 256, 0, stream>>>(x, xb, BS_ * HID_ / 4);
    dim3 tb(32, 8);
    k_transpose_cvt<<<dim3(HID_ / 32, NQA_P / 32), tb, 0, stream>>>(q_a_w, qa_wt, HID_, QLORA_, HID_);
    k_transpose_cvt<<<dim3(HID_ / 32, NKVA_P / 32), tb, 0, stream>>>(kv_a_w, kva_wt, HID_, KVLORA_ + ROPE_, HID_);
    k_transpose_cvt<<<dim3(QLORA_P / 32, 2048 / 32), tb, 0, stream>>>(q_b_w, qb_wt, QLORA_, 2048, QLORA_P);
    k_transpose_cvt<<<dim3(KVLORA_ / 32, 3072 / 32), tb, 0, stream>>>(kv_b_w, kvb_wt, KVLORA_, 3072, KVLORA_);
    k_transpose_cvt<<<dim3(2048 / 32, 2048 / 32), tb, 0, stream>>>(o_w, ow_t, 2048, 2048, 2048);
    k_rope_table<<<S_ * 32 / 256, 256, 0, stream>>>(ct, st);

    // stage 1: down-projections
    gemm_bt<bf16><<<dim3(NQA_P / 128, BS_ / 128), 256, 0, stream>>>(xb, qa_wt, qa, HID_, HID_, HID_, NQA_P);
    gemm_bt<bf16><<<dim3(NKVA_P / 128, BS_ / 128), 256, 0, stream>>>(xb, kva_wt, ckvkpe, HID_, HID_, HID_, NKVA_P);

    // stage 2: rmsnorms + k_pe rope
    k_rms_rope<<<BS_, 256, 0, stream>>>(qa, ckvkpe, q_a_ln, kv_a_ln, ct, st, qan, ckvn, kr);

    // stage 3: up-projections
    gemm_bt<bf16><<<dim3(2048 / 128, BS_ / 128), 256, 0, stream>>>(qan, qb_wt, qfull, QLORA_P, QLORA_P, QLORA_P, 2048);
    gemm_bt<bf16><<<dim3(3072 / 128, BS_ / 128), 256, 0, stream>>>(ckvn, kvb_wt, kvfull, KVLORA_, KVLORA_, KVLORA_, 3072);

    // stage 4: assemble attention operands (K is gathered in-flash now)
    k_build_q<<<dim3(BS_, NH_), 128, 0, stream>>>(qfull, ct, st, Qf);
    k_build_vt<<<dim3(B_ * NH_, S_ / 64), 256, 0, stream>>>(kvfull, Vt);

    // stage 5: causal flash attention (qb paired for CU work balance)
    k_flash<<<dim3(B_ * NH_, S_ / 128), 512, 0, stream>>>(Qf, kvfull, kr, Vt, attn);

    // stage 6: output projection (f32 out)
    gemm_bt<float><<<dim3(2048 / 128, BS_ / 128), 256, 0, stream>>>(attn, ow_t, out, HID_, HID_, HID_, 2048);
}

// Round 4
// 275.956 us; speedup vs baseline: 1.8553x; 1.2440x over previous
//
#include <hip/hip_runtime.h>
#include <hip/hip_bf16.h>

typedef __attribute__((ext_vector_type(8))) short short8;   // 8 x bf16 (MFMA A/B frag)
typedef __attribute__((ext_vector_type(4))) float f32x4;    // MFMA C/D frag

using bf16 = __hip_bfloat16;

static constexpr int B_ = 2, S_ = 2048, HID_ = 2048, NH_ = 16;
static constexpr int ROPE_ = 64, VDIM_ = 128, QHEAD_ = 128;
static constexpr int QLORA_ = 682, KVLORA_ = 256;
static constexpr int QLORA_P = 704;   // K padded to mult of 64
static constexpr int NQA_P = 768;     // q_a N padded
static constexpr int NKVA_P = 384;    // kv_a N padded
static constexpr int NA_ = NQA_P + NKVA_P;   // 1152 merged down-proj N
static constexpr float THETA_ = 128000.0f;
static constexpr float SCALE_ = 0.08838834764831845f;  // 1/sqrt(128)
static constexpr float EPS_ = 1e-6f;
static constexpr int BS_ = B_ * S_;   // 4096

// async global->LDS, 16B per lane. Dest must be linear in lane order
// (wave-uniform base + lane*16); source is per-lane (may be swizzled/gathered).
__device__ __forceinline__ void gl2lds16(const void* g, void* l) {
    __builtin_amdgcn_global_load_lds(
        (const __attribute__((address_space(1))) unsigned int*)g,
        (__attribute__((address_space(3))) unsigned int*)l, 16, 0, 0);
}

// ---------------- misc: x f32->bf16 convert + rope cos/sin table ---------------
struct bf16x4_s { bf16 x, y, z, w; };

__global__ void k_misc(const float* __restrict__ x, bf16* __restrict__ xb,
                       float* __restrict__ ct, float* __restrict__ st) {
    int bid = blockIdx.x, t = threadIdx.x;
    if (bid < 8192) {                          // convert BS*HID f32 -> bf16, 4/thread
        int i = bid * 256 + t;
        float4 v = reinterpret_cast<const float4*>(x)[i];
        bf16x4_s o;
        o.x = __float2bfloat16(v.x); o.y = __float2bfloat16(v.y);
        o.z = __float2bfloat16(v.z); o.w = __float2bfloat16(v.w);
        reinterpret_cast<bf16x4_s*>(xb)[i] = o;
    } else {                                   // rope table [S][32]
        int idx = (bid - 8192) * 256 + t;      // S*32 = 65536
        int tpos = idx >> 5, j = idx & 31;
        float inv = expf(-(float)j * (logf(THETA_) / 32.0f));
        float f = (float)tpos * inv;
        ct[idx] = cosf(f);
        st[idx] = sinf(f);
    }
}

// ---------------- merged weight transposes: W[K][N] f32 -> Wt[Nd][Kpad] bf16 --
struct TD { const float* src; bf16* dst; int Ksrc, Nsrc, Kpad, tilesX, off, perm; };
struct TDs { TD d[5]; };

__global__ void k_prep_w(TDs P) {
    __shared__ float tile[32][33];
    int flat = blockIdx.x;
    int di = 0;
    #pragma unroll
    for (int i = 1; i < 5; ++i) if (flat >= P.d[i].off) di = i;
    TD d = P.d[di];
    int local = flat - d.off;
    int xt = local % d.tilesX, yt = local / d.tilesX;
    int kb = xt * 32, nb = yt * 32;
    int tx = threadIdx.x, ty = threadIdx.y;          // 32 x 8
    #pragma unroll
    for (int i = 0; i < 32; i += 8) {
        int k = kb + ty + i, n = nb + tx;
        tile[ty + i][tx] = (k < d.Ksrc && n < d.Nsrc) ? d.src[(size_t)k * d.Nsrc + n] : 0.0f;
    }
    __syncthreads();
    #pragma unroll
    for (int i = 0; i < 32; i += 8) {
        int n = nb + ty + i, k = kb + tx;
        int nd = n;
        if (d.perm) {                          // kv_b: h*192+(knope 64|v 128) -> [knope 1024 | v 2048]
            int h = n / 192, dd = n - h * 192;
            nd = (dd < 64) ? h * 64 + dd : 1024 + h * 128 + (dd - 64);
        }
        d.dst[(size_t)nd * d.Kpad + k] = __float2bfloat16(tile[tx][ty + i]);
    }
}

// ---------------- GEMM: C[M][N] = A[M][K] * Bt[N][K]^T  (bf16, f32 acc) -------
// 128x128 tile, BK=64, 4 waves (2x2), 4x4 16x16x32 frags/wave.
// LDS [128 rows][8 chunks of 16B], phys chunk = ch ^ (row&7). gl2lds staging.
#define GEMM_PROLOGUE(Aptr, Bptr, LDA, LDB, KDIM)                                        \
    __shared__ bf16 As[128 * 64];                                                        \
    __shared__ bf16 Bs[128 * 64];                                                        \
    const int t = threadIdx.x;                                                           \
    const int lane = t & 63, w = t >> 6;                                                 \
    const int l15 = lane & 15, l4 = lane >> 4;                                           \
    const int wr = (w >> 1) * 64, wc = (w & 1) * 64;                                     \
    const int m0 = blockIdx.y * 128, n0 = blockIdx.x * 128;                              \
    f32x4 acc[4][4] = {};                                                                \
    for (int k0 = 0; k0 < (KDIM); k0 += 64) {                                            \
        _Pragma("unroll")                                                                \
        for (int i = 0; i < 4; ++i) {                                                    \
            int cid = t + i * 256;                                                       \
            int row = cid >> 3;                                                          \
            int ch = (cid & 7) ^ (row & 7);                                              \
            gl2lds16((Aptr) + (size_t)(m0 + row) * (LDA) + k0 + ch * 8,                  \
                     reinterpret_cast<char*>(As) + cid * 16);                            \
            gl2lds16((Bptr) + (size_t)(n0 + row) * (LDB) + k0 + ch * 8,                  \
                     reinterpret_cast<char*>(Bs) + cid * 16);                            \
        }                                                                                \
        __syncthreads();                                                                 \
        _Pragma("unroll")                                                                \
        for (int kk = 0; kk < 2; ++kk) {                                                 \
            short8 a[4], b[4];                                                           \
            _Pragma("unroll")                                                            \
            for (int m = 0; m < 4; ++m) {                                                \
                int row = wr + m * 16 + l15;                                             \
                int ch = (kk * 4 + l4) ^ (row & 7);                                      \
                a[m] = *reinterpret_cast<const short8*>(                                 \
                    reinterpret_cast<const char*>(As) + row * 128 + ch * 16);            \
            }                                                                            \
            _Pragma("unroll")                                                            \
            for (int n = 0; n < 4; ++n) {                                                \
                int row = wc + n * 16 + l15;                                             \
                int ch = (kk * 4 + l4) ^ (row & 7);                                      \
                b[n] = *reinterpret_cast<const short8*>(                                 \
                    reinterpret_cast<const char*>(Bs) + row * 128 + ch * 16);            \
            }                                                                            \
            _Pragma("unroll")                                                            \
            for (int m = 0; m < 4; ++m)                                                  \
                _Pragma("unroll")                                                        \
                for (int n = 0; n < 4; ++n)                                              \
                    acc[m][n] = __builtin_amdgcn_mfma_f32_16x16x32_bf16(a[m], b[n],      \
                                                                       acc[m][n], 0, 0, 0); \
        }                                                                                \
        __syncthreads();                                                                 \
    }
// C/D layout: col = lane&15, row = (lane>>4)*4 + reg  [verified m89/m91]

template <typename OutT>
__launch_bounds__(256)
__global__ void gemm_bt(const bf16* __restrict__ A, const bf16* __restrict__ Bt,
                        OutT* __restrict__ C, int K, int lda, int ldb, int ldc)
{
    GEMM_PROLOGUE(A, Bt, lda, ldb, K)
    #pragma unroll
    for (int m = 0; m < 4; ++m)
        #pragma unroll
        for (int n = 0; n < 4; ++n)
            #pragma unroll
            for (int j = 0; j < 4; ++j) {
                int r = m0 + wr + m * 16 + l4 * 4 + j;
                int c = n0 + wc + n * 16 + l15;
                float v = acc[m][n][j];
                if constexpr (sizeof(OutT) == 2) C[(size_t)r * ldc + c] = __float2bfloat16(v);
                else                             C[(size_t)r * ldc + c] = v;
            }
}

// ---------------- q_b GEMM with fused RoPE + (b,h,s,d) scatter epilogue -------
// N-tile == one head (128 cols). Waves with wc=0 hold nope cols, wc=64 pe cols.
__launch_bounds__(256)
__global__ void gemm_qb_rope(const bf16* __restrict__ A, const bf16* __restrict__ Bt,
                             const float* __restrict__ ct, const float* __restrict__ st,
                             bf16* __restrict__ Qf)
{
    GEMM_PROLOGUE(A, Bt, QLORA_P, QLORA_P, QLORA_P)
    const int h = blockIdx.x;                  // head
    if (wc == 0) {
        #pragma unroll
        for (int m = 0; m < 4; ++m)
            #pragma unroll
            for (int n = 0; n < 4; ++n)
                #pragma unroll
                for (int j = 0; j < 4; ++j) {
                    int r = m0 + wr + m * 16 + l4 * 4 + j;
                    int c = n * 16 + l15;                       // [0,64) nope
                    int s = r & (S_ - 1), bq = r >> 11;
                    Qf[((size_t)(bq * NH_ + h) * S_ + s) * 128 + c] =
                        __float2bfloat16(acc[m][n][j]);
                }
    } else {
        #pragma unroll
        for (int m = 0; m < 4; ++m)
            #pragma unroll
            for (int n = 0; n < 4; ++n)
                #pragma unroll
                for (int j = 0; j < 4; ++j) {
                    int r = m0 + wr + m * 16 + l4 * 4 + j;
                    int p = n * 16 + l15;                       // pe-local [0,64)
                    int jj = p >> 1, odd = p & 1;
                    float v = acc[m][n][j];
                    float pr = __shfl_xor(v, 1);
                    float e0 = odd ? pr : v, e1 = odd ? v : pr;
                    int s = r & (S_ - 1), bq = r >> 11;
                    float c_ = ct[s * 32 + jj], s_ = st[s * 32 + jj];
                    float ov = odd ? (e1 * c_ + e0 * s_) : (e0 * c_ - e1 * s_);
                    int c_out = 64 + (odd ? 32 : 0) + jj;
                    Qf[((size_t)(bq * NH_ + h) * S_ + s) * 128 + c_out] =
                        __float2bfloat16(ov);
                }
    }
}

// ---------------- kv_b GEMM (permuted weights): knope + direct-V^T epilogue ---
// n0 < 1024: k_nope -> knope[bs][1024]. n0 >= 1024: head tile -> Vt[bh][128][S].
__launch_bounds__(256)
__global__ void gemm_kvb_split(const bf16* __restrict__ A, const bf16* __restrict__ Bt,
                               bf16* __restrict__ knope, bf16* __restrict__ Vt)
{
    GEMM_PROLOGUE(A, Bt, KVLORA_, KVLORA_, KVLORA_)
    if (n0 < 1024) {
        #pragma unroll
        for (int m = 0; m < 4; ++m)
            #pragma unroll
            for (int n = 0; n < 4; ++n)
                #pragma unroll
                for (int j = 0; j < 4; ++j) {
                    int r = m0 + wr + m * 16 + l4 * 4 + j;
                    int c = n0 + wc + n * 16 + l15;
                    knope[(size_t)r * 1024 + c] = __float2bfloat16(acc[m][n][j]);
                }
    } else {
        const int h = (n0 - 1024) >> 7;
        const int bq = m0 >> 11;               // uniform per block (128-row tile)
        const int bh = bq * NH_ + h;
        #pragma unroll
        for (int m = 0; m < 4; ++m)
            #pragma unroll
            for (int n = 0; n < 4; ++n) {
                int cl = wc + n * 16 + l15;    // d within head
                int rb = m0 + wr + m * 16 + l4 * 4;
                int s = rb & (S_ - 1);
                ushort4 pk;
                {
                    bf16 h0 = __float2bfloat16(acc[m][n][0]);
                    bf16 h1 = __float2bfloat16(acc[m][n][1]);
                    bf16 h2 = __float2bfloat16(acc[m][n][2]);
                    bf16 h3 = __float2bfloat16(acc[m][n][3]);
                    pk.x = *reinterpret_cast<unsigned short*>(&h0);
                    pk.y = *reinterpret_cast<unsigned short*>(&h1);
                    pk.z = *reinterpret_cast<unsigned short*>(&h2);
                    pk.w = *reinterpret_cast<unsigned short*>(&h3);
                }
                *reinterpret_cast<ushort4*>(Vt + ((size_t)bh * 128 + cl) * S_ + s) = pk;
            }
    }
}

// ---------------- fused rmsnorm(q_a), rmsnorm(ckv), rope(k_pe) ----------------
__launch_bounds__(256)
__global__ void k_rms_rope(const bf16* __restrict__ qac,
                           const float* __restrict__ qln, const float* __restrict__ kvln,
                           const float* __restrict__ ct, const float* __restrict__ st,
                           bf16* __restrict__ qan, bf16* __restrict__ ckvn, bf16* __restrict__ kr)
{
    __shared__ float red[8];
    int bs = blockIdx.x;
    int t = threadIdx.x, lane = t & 63, w = t >> 6;
    int s = bs & (S_ - 1);
    const bf16* qrow = qac + (size_t)bs * NA_;
    const bf16* crow = qrow + NQA_P;
    float sq = 0.f, sk;
    for (int c = t; c < QLORA_; c += 256) { float v = __bfloat162float(qrow[c]); sq += v * v; }
    { float v = __bfloat162float(crow[t]); sk = v * v; }          // t in [0,256) covers all
    #pragma unroll
    for (int m = 1; m < 64; m <<= 1) { sq += __shfl_xor(sq, m); sk += __shfl_xor(sk, m); }
    if (lane == 0) { red[w] = sq; red[4 + w] = sk; }
    __syncthreads();
    sq = red[0] + red[1] + red[2] + red[3];
    sk = red[4] + red[5] + red[6] + red[7];
    float qs = rsqrtf(sq / (float)QLORA_ + EPS_);
    float ks = rsqrtf(sk / (float)KVLORA_ + EPS_);
    for (int c = t; c < QLORA_P; c += 256)
        qan[(size_t)bs * QLORA_P + c] =
            (c < QLORA_) ? __float2bfloat16(__bfloat162float(qrow[c]) * qs * qln[c])
                         : __float2bfloat16(0.0f);
    ckvn[(size_t)bs * KVLORA_ + t] = __float2bfloat16(__bfloat162float(crow[t]) * ks * kvln[t]);
    if (t < 64) {
        int j = t & 31;
        float c_ = ct[s * 32 + j], s_ = st[s * 32 + j];
        float e0 = __bfloat162float(crow[KVLORA_ + 2 * j]);      // de-interleaved RoPE
        float e1 = __bfloat162float(crow[KVLORA_ + 2 * j + 1]);
        float v = (t < 32) ? (e0 * c_ - e1 * s_) : (e1 * c_ + e0 * s_);
        kr[(size_t)bs * 64 + t] = __float2bfloat16(v);
    }
}

// ---------------- causal flash attention --------------------------------------
// block = 128 q-rows x (b,h). 8 waves, each owns 16 q-rows. Q in registers.
// K gathered from knope+kr; V from Vt. Double-buffered, one barrier per tile.
// Staging addresses hoisted: per-lane pointers advanced by constant stride.
__launch_bounds__(512, 4)
__global__ void k_flash(const bf16* __restrict__ Qf, const bf16* __restrict__ knope,
                        const bf16* __restrict__ kr, const bf16* __restrict__ Vt,
                        bf16* __restrict__ attn_out)
{
    __shared__ bf16 Ks[2][64 * 128];      // [64 k-rows][16 chunks], swz ch^(row&7)
    __shared__ bf16 Vs[2][128 * 64];      // [128 d-rows][8 chunks]
    __shared__ bf16 Ps[8][16 * 64];       // per-wave P strip [16 rows][8 chunks]

    const int t = threadIdx.x, lane = t & 63, w = t >> 6;
    const int l15 = lane & 15, l4 = lane >> 4;
    // pair qb's so the 2 co-resident blocks/CU sum to ~constant work
    const int qb = (blockIdx.y < 8) ? blockIdx.y : (23 - blockIdx.y);
    const int bh = blockIdx.x;
    const int q0 = qb * 128;
    const int b = bh >> 4, h = bh & 15;
    const int r0 = q0 + w * 16;           // wave's first q-row

    // Q -> registers (one-time strided read; L2/L3 absorbs)
    short8 qa_[4];
    {
        const bf16* qrow = Qf + ((size_t)bh * S_ + r0 + l15) * 128;
        #pragma unroll
        for (int kk = 0; kk < 4; ++kk)
            qa_[kk] = *reinterpret_cast<const short8*>(qrow + kk * 32 + l4 * 8);
    }

    // hoisted per-lane staging sources (advance by constant stride per tile)
    const bf16 *kSrc0, *kSrc1, *vSrc0, *vSrc1;
    size_t kStp0, kStp1;
    {
        int cid = t, row = cid >> 4, ch = (cid & 15) ^ (row & 7);
        kSrc0 = (ch < 8) ? knope + (size_t)(b * S_ + row) * 1024 + h * 64 + ch * 8
                         : kr + (size_t)(b * S_ + row) * 64 + (ch - 8) * 8;
        kStp0 = (ch < 8) ? (size_t)64 * 1024 : (size_t)64 * 64;
    }
    {
        int cid = t + 512, row = cid >> 4, ch = (cid & 15) ^ (row & 7);
        kSrc1 = (ch < 8) ? knope + (size_t)(b * S_ + row) * 1024 + h * 64 + ch * 8
                         : kr + (size_t)(b * S_ + row) * 64 + (ch - 8) * 8;
        kStp1 = (ch < 8) ? (size_t)64 * 1024 : (size_t)64 * 64;
    }
    {
        const bf16* Vg = Vt + (size_t)bh * 128 * S_;
        int cid = t, row = cid >> 3, ch = (cid & 7) ^ (row & 7);
        vSrc0 = Vg + (size_t)row * S_ + ch * 8;
        cid = t + 512; row = cid >> 3; ch = (cid & 7) ^ (row & 7);
        vSrc1 = Vg + (size_t)row * S_ + ch * 8;
    }
    auto stage = [&](int buf) {
        gl2lds16(kSrc0, reinterpret_cast<char*>(Ks[buf]) + t * 16);
        gl2lds16(kSrc1, reinterpret_cast<char*>(Ks[buf]) + (t + 512) * 16);
        gl2lds16(vSrc0, reinterpret_cast<char*>(Vs[buf]) + t * 16);
        gl2lds16(vSrc1, reinterpret_cast<char*>(Vs[buf]) + (t + 512) * 16);
        kSrc0 += kStp0; kSrc1 += kStp1; vSrc0 += 64; vSrc1 += 64;
    };

    const int NT = qb * 2 + 2;                     // 64-wide K tiles
    stage(0);
    __syncthreads();

    f32x4 o[8] = {};
    float m_r[4], l_r[4];
    #pragma unroll
    for (int j = 0; j < 4; ++j) { m_r[j] = -1e30f; l_r[j] = 0.f; }
    const float SCL2 = SCALE_ * 1.4426950408889634f;   // fold log2(e): exp2 softmax

    int cur = 0;
    for (int kb = 0; kb < NT; ++kb) {
        const int k0 = kb * 64;
        if (kb + 1 < NT) stage(cur ^ 1);

        if (k0 <= r0 + 15) {                       // skip fully-masked tiles for this wave
            // S strip = Q(16x128) @ K^T(128x64)
            f32x4 sfr[4] = {};
            __builtin_amdgcn_s_setprio(1);
            #pragma unroll
            for (int kk = 0; kk < 4; ++kk) {
                short8 bfr[4];
                #pragma unroll
                for (int n = 0; n < 4; ++n) {
                    int row = n * 16 + l15;
                    int ch = (kk * 4 + l4) ^ (row & 7);
                    bfr[n] = *reinterpret_cast<const short8*>(
                        reinterpret_cast<const char*>(Ks[cur]) + row * 256 + ch * 16);
                }
                #pragma unroll
                for (int n = 0; n < 4; ++n)
                    sfr[n] = __builtin_amdgcn_mfma_f32_16x16x32_bf16(qa_[kk], bfr[n], sfr[n], 0, 0, 0);
            }
            __builtin_amdgcn_s_setprio(0);

            const bool needMask = (k0 + 63 > r0);
            #pragma unroll
            for (int n = 0; n < 4; ++n)
                #pragma unroll
                for (int j = 0; j < 4; ++j) {
                    float v = sfr[n][j] * SCL2;            // log2-domain score
                    if (needMask) {
                        int col = k0 + n * 16 + l15;
                        int row = r0 + l4 * 4 + j;
                        if (col > row) v = -1e30f;
                    }
                    sfr[n][j] = v;
                }

            // online max with defer-rescale (T13, THR=8 in log2 domain)
            float rm[4];
            bool grow = false;
            #pragma unroll
            for (int j = 0; j < 4; ++j) {
                float r = fmaxf(fmaxf(sfr[0][j], sfr[1][j]), fmaxf(sfr[2][j], sfr[3][j]));
                r = fmaxf(r, __shfl_xor(r, 1));
                r = fmaxf(r, __shfl_xor(r, 2));
                r = fmaxf(r, __shfl_xor(r, 4));
                r = fmaxf(r, __shfl_xor(r, 8));
                rm[j] = r;
                grow |= (r > m_r[j] + 8.0f);
            }
            if (__ballot(grow)) {
                #pragma unroll
                for (int j = 0; j < 4; ++j) {
                    float mn = fmaxf(m_r[j], rm[j]);
                    float alpha = exp2f(m_r[j] - mn);
                    m_r[j] = mn;
                    l_r[j] *= alpha;
                    #pragma unroll
                    for (int n = 0; n < 8; ++n) o[n][j] *= alpha;
                }
            }

            char* pb = reinterpret_cast<char*>(Ps[w]);
            #pragma unroll
            for (int j = 0; j < 4; ++j) {
                float rs = 0.f;
                #pragma unroll
                for (int n = 0; n < 4; ++n) {
                    float p = exp2f(sfr[n][j] - m_r[j]);
                    sfr[n][j] = p;
                    rs += p;
                }
                rs += __shfl_xor(rs, 1); rs += __shfl_xor(rs, 2);
                rs += __shfl_xor(rs, 4); rs += __shfl_xor(rs, 8);
                l_r[j] += rs;
                int row = l4 * 4 + j;
                #pragma unroll
                for (int n = 0; n < 4; ++n) {
                    int col = n * 16 + l15;
                    int ch = (col >> 3) ^ (row & 7);
                    *reinterpret_cast<bf16*>(pb + row * 128 + ch * 16 + (col & 7) * 2) =
                        __float2bfloat16(sfr[n][j]);
                }
            }
            // O += P(16x64) @ V(64x128)
            __builtin_amdgcn_s_setprio(1);
            #pragma unroll
            for (int kk = 0; kk < 2; ++kk) {
                int pch = (kk * 4 + l4) ^ (l15 & 7);
                short8 pa = *reinterpret_cast<const short8*>(pb + l15 * 128 + pch * 16);
                #pragma unroll
                for (int n = 0; n < 8; ++n) {
                    int row = n * 16 + l15;
                    int ch = (kk * 4 + l4) ^ (row & 7);
                    short8 vb = *reinterpret_cast<const short8*>(
                        reinterpret_cast<const char*>(Vs[cur]) + row * 128 + ch * 16);
                    o[n] = __builtin_amdgcn_mfma_f32_16x16x32_bf16(pa, vb, o[n], 0, 0, 0);
                }
            }
            __builtin_amdgcn_s_setprio(0);
        }
        __syncthreads();     // drains next-tile loads (they flew under compute) + syncs
        cur ^= 1;
    }

    size_t obase = ((size_t)(b * S_) + q0 + w * 16) * (size_t)(NH_ * VDIM_) + h * VDIM_;
    #pragma unroll
    for (int n = 0; n < 8; ++n)
        #pragma unroll
        for (int j = 0; j < 4; ++j) {
            int r = l4 * 4 + j;
            int c = n * 16 + l15;
            attn_out[obase + (size_t)r * (NH_ * VDIM_) + c] = __float2bfloat16(o[n][j] / l_r[j]);
        }
}

// ==============================================================================
extern "C" void kernel_launch(void* const* d_in, const int* in_sizes, int n_in,
                              void* d_out, int out_size, void* d_ws, size_t ws_size,
                              hipStream_t stream)
{
    (void)in_sizes; (void)n_in; (void)out_size;
    const float* x       = (const float*)d_in[0];
    const float* q_a_w   = (const float*)d_in[1];
    const float* q_a_ln  = (const float*)d_in[2];
    const float* q_b_w   = (const float*)d_in[3];
    const float* kv_a_w  = (const float*)d_in[4];
    const float* kv_a_ln = (const float*)d_in[5];
    const float* kv_b_w  = (const float*)d_in[6];
    const float* o_w     = (const float*)d_in[7];
    float* out = (float*)d_out;

    char* ws = (char*)d_ws;
    size_t off = 0;
    auto alloc = [&](size_t bytes) -> char* {
        char* p = ws + off;
        off += (bytes + 255) & ~(size_t)255;
        return p;
    };

    bf16* xb     = (bf16*)alloc((size_t)BS_ * HID_ * 2);        // reused as Qf after gemm_a
    bf16* a_wt   = (bf16*)alloc((size_t)NA_ * HID_ * 2);        // merged [q_a | kv_a]^T
    bf16* qb_wt  = (bf16*)alloc((size_t)2048 * QLORA_P * 2);
    bf16* kvb_wt = (bf16*)alloc((size_t)3072 * KVLORA_ * 2);    // permuted cols
    bf16* ow_t   = (bf16*)alloc((size_t)2048 * 2048 * 2);
    float* ct    = (float*)alloc((size_t)S_ * 32 * 4);
    float* st    = (float*)alloc((size_t)S_ * 32 * 4);
    bf16* qac    = (bf16*)alloc((size_t)BS_ * NA_ * 2);         // down-proj out [qa|ckvkpe]
    bf16* qan    = (bf16*)alloc((size_t)BS_ * QLORA_P * 2);
    bf16* ckvn   = (bf16*)alloc((size_t)BS_ * KVLORA_ * 2);
    bf16* kr     = (bf16*)alloc((size_t)BS_ * 64 * 2);
    bf16* knope  = (bf16*)alloc((size_t)BS_ * 1024 * 2);
    bf16* Vt     = (bf16*)alloc((size_t)BS_ * 2048 * 2);        // [bh][128][S]
    bf16* attn   = (bf16*)alloc((size_t)BS_ * 2048 * 2);

    bf16* Qf = xb;   // xb dead after gemm_a

    if (ws_size < off) return;  // diagnostic guard: absmax would stay exactly 3.468750

    // stage 0: convert x + rope tables; merged weight transposes
    k_misc<<<8192 + 256, 256, 0, stream>>>(x, xb, ct, st);
    TDs P;
    //              src      dst                    Ksrc  Nsrc  Kpad  tX  off   perm
    P.d[0] = TD{ q_a_w,  a_wt,                      2048,  682, 2048, 64,    0, 0 };  // 64x24
    P.d[1] = TD{ kv_a_w, a_wt + (size_t)NQA_P*2048, 2048,  320, 2048, 64, 1536, 0 };  // 64x12
    P.d[2] = TD{ q_b_w,  qb_wt,                      682, 2048,  704, 22, 2304, 0 };  // 22x64
    P.d[3] = TD{ kv_b_w, kvb_wt,                     256, 3072,  256,  8, 3712, 1 };  // 8x96
    P.d[4] = TD{ o_w,    ow_t,                      2048, 2048, 2048, 64, 4480, 0 };  // 64x64
    k_prep_w<<<8576, dim3(32, 8), 0, stream>>>(P);

    // stage 1: merged down-projection  qac = x @ [q_a|kv_a]
    gemm_bt<bf16><<<dim3(NA_ / 128, BS_ / 128), 256, 0, stream>>>(xb, a_wt, qac,
                                                                  HID_, HID_, HID_, NA_);

    // stage 2: rmsnorms + k_pe rope
    k_rms_rope<<<BS_, 256, 0, stream>>>(qac, q_a_ln, kv_a_ln, ct, st, qan, ckvn, kr);

    // stage 3: up-projections with fused epilogues
    gemm_qb_rope<<<dim3(2048 / 128, BS_ / 128), 256, 0, stream>>>(qan, qb_wt, ct, st, Qf);
    gemm_kvb_split<<<dim3(3072 / 128, BS_ / 128), 256, 0, stream>>>(ckvn, kvb_wt, knope, Vt);

    // stage 4: causal flash attention (qb paired for CU work balance)
    k_flash<<<dim3(B_ * NH_, S_ / 128), 512, 0, stream>>>(Qf, knope, kr, Vt, attn);

    // stage 5: output projection (f32 out)
    gemm_bt<float><<<dim3(2048 / 128, BS_ / 128), 256, 0, stream>>>(attn, ow_t, out,
                                                                    HID_, HID_, HID_, 2048);
}